// Round 7
// baseline (227.014 us; speedup 1.0000x reference)
//
#include <hip/hip_runtime.h>
#include <math.h>

#define D_MODEL   1024
#define NUM_HEADS 16
#define HEAD_DIM  64
#define BS        64
#define NB        32
#define S_LEN     2048
#define BATCH     2
#define M_ROWS    (BATCH * S_LEN)  // 4096
#define THRESH    0.99f
#define SCEXP     0.18033688f      // 0.125 * log2(e): p = exp2(score_raw * SCEXP)
#define NPH       (BATCH * NB * NUM_HEADS)   // 1024 (pair,head) work items

typedef __attribute__((ext_vector_type(8))) short bf16x8;
typedef __attribute__((ext_vector_type(8))) _Float16 f16x8;
typedef __attribute__((ext_vector_type(2))) __fp16 fp16v2;   // native return type of cvt_pkrtz
typedef __attribute__((ext_vector_type(4))) float f32x4;

static constexpr size_t QKV_ELEMS = (size_t)BATCH * NUM_HEADS * S_LEN * HEAD_DIM; // 4 Mi elems

__device__ __forceinline__ unsigned short f2bf(float f) {
    unsigned int u = __float_as_uint(f);
    u += 0x7fff + ((u >> 16) & 1);   // RNE
    return (unsigned short)(u >> 16);
}

__device__ __forceinline__ unsigned int pkrtz(float a, float b) {
    fp16v2 r = __builtin_amdgcn_cvt_pkrtz(a, b);   // v_cvt_pkrtz_f16_f32, 1 instr
    return __builtin_bit_cast(unsigned int, r);
}

// async global->LDS, 16B per lane; lds dest = wave-uniform base + lane*16
__device__ __forceinline__ void gload16(const void* gptr, void* lptr) {
    __builtin_amdgcn_global_load_lds(
        (const __attribute__((address_space(1))) void*)gptr,
        (__attribute__((address_space(3))) void*)lptr, 16, 0, 0);
}

// ---------------- fused prep: convert_x | transpose_w | compact ----------------
// blocks [0,2048): x fp32->bf16 ; [2048,3072): W transpose ; [3072]: keep+worklist
__global__ __launch_bounds__(256) void prep_kernel(
    const float* __restrict__ x, const float* __restrict__ G,
    const float* __restrict__ Wq, const float* __restrict__ Wk,
    const float* __restrict__ Wv, const float* __restrict__ Wo,
    unsigned short* __restrict__ xb, unsigned short* __restrict__ wcat,
    unsigned short* __restrict__ wot, int* __restrict__ keep, int* __restrict__ work)
{
    const int bid = blockIdx.x, tid = threadIdx.x;
    __shared__ float T[64][65];

    if (bid < 2048) {                       // ---- convert x ----
        size_t i = ((size_t)bid * 256 + tid) * 8;
        float4 a = *(const float4*)(x + i);
        float4 b = *(const float4*)(x + i + 4);
        uint4 o;
        o.x = (unsigned int)f2bf(a.x) | ((unsigned int)f2bf(a.y) << 16);
        o.y = (unsigned int)f2bf(a.z) | ((unsigned int)f2bf(a.w) << 16);
        o.z = (unsigned int)f2bf(b.x) | ((unsigned int)f2bf(b.y) << 16);
        o.w = (unsigned int)f2bf(b.z) | ((unsigned int)f2bf(b.w) << 16);
        *(uint4*)(xb + i) = o;
    } else if (bid < 3072) {                // ---- transpose W ----
        int i = bid - 2048;
        int mat = i >> 8, rem = i & 255;
        int k0 = (rem & 15) * 64, n0 = (rem >> 4) * 64;
        const float* W = (mat == 0) ? Wq : (mat == 1) ? Wk : (mat == 2) ? Wv : Wo;
        int rr = tid >> 4, c4 = (tid & 15) * 4;
        #pragma unroll
        for (int j = 0; j < 4; j++) {
            int row = rr + j * 16;
            float4 v = *(const float4*)(W + (size_t)(k0 + row) * 1024 + n0 + c4);
            T[row][c4 + 0] = v.x; T[row][c4 + 1] = v.y;
            T[row][c4 + 2] = v.z; T[row][c4 + 3] = v.w;
        }
        __syncthreads();
        unsigned short* dst = (mat < 3) ? (wcat + (size_t)mat * 1024 * 1024) : wot;
        #pragma unroll
        for (int j = 0; j < 4; j++) {
            int n = rr + j * 16;
            unsigned int lo = (unsigned int)f2bf(T[c4 + 0][n]) | ((unsigned int)f2bf(T[c4 + 1][n]) << 16);
            unsigned int hi = (unsigned int)f2bf(T[c4 + 2][n]) | ((unsigned int)f2bf(T[c4 + 3][n]) << 16);
            *(uint2*)(dst + (size_t)(n0 + n) * 1024 + k0 + c4) = make_uint2(lo, hi);
        }
    } else {                                // ---- compact (wave 0 only) ----
        if (tid < 64) {
            int t = tid;
            const float4* g = (const float4*)(G + (size_t)t * 64);
            float mx = 0.f;
            #pragma unroll
            for (int j = 0; j < 16; j++) {
                float4 v = g[j];
                mx = fmaxf(mx, fmaxf(fmaxf(fabsf(v.x), fabsf(v.y)), fmaxf(fabsf(v.z), fabsf(v.w))));
            }
            bool k = (mx >= THRESH);
            unsigned long long bal = __ballot(k);
            int nk = __popcll(bal);
            unsigned long long below = bal & ((1ull << t) - 1ull);
            int nbelow = (int)__popcll(below);
            keep[t] = k ? 1 : 0;
            if (t == 0) work[0] = nk;
            int pos = k ? nbelow : (nk + t - nbelow);
            work[1 + pos] = t;
        }
    }
}

// ---------------- bf16 MFMA GEMM (double-buffered): C = A[M][1024] @ Bt[N][1024]^T ----------------
// mode 0: fp32 out0 + b0; dropped tiles write bias rows.
// mode 1: fused QKV. kind 0->q(bf16), 1->k(bf16), 2->V^T(fp16, transposed global layout).
__global__ __launch_bounds__(256) void mfma_gemm(
    const unsigned short* __restrict__ A, const unsigned short* __restrict__ Bt,
    const float* __restrict__ b0, const float* __restrict__ b1, const float* __restrict__ b2,
    const int* __restrict__ keep,
    void* __restrict__ out0, unsigned short* __restrict__ out1, unsigned short* __restrict__ out2,
    int mode)
{
    const int K = 1024;
    const int n0 = blockIdx.x * 128, m0 = blockIdx.y * 128;
    const int tid = threadIdx.x, w = tid >> 6, lane = tid & 63;
    const int quad = lane >> 4, l16 = lane & 15;
    const int wm = w >> 1, wn = w & 1;

    const int kb0 = m0 >> 6;
    const bool dropped = (!keep[kb0]) && (!keep[kb0 + 1]);

    if (mode == 1 && (n0 >> 10) == 0 && dropped) return;
    if (mode == 0 && dropped) {
        float* o = (float*)out0;
        #pragma unroll
        for (int i = 0; i < 16; i++) {
            int u = tid + i * 256;
            int row = u >> 5, c = (u & 31) * 4;
            *(float4*)(o + (size_t)(m0 + row) * 1024 + n0 + c) = *(const float4*)(b0 + n0 + c);
        }
        return;
    }

    __shared__ unsigned short Asl[2][128 * 32];
    __shared__ unsigned short Bsl[2][128 * 32];

    f32x4 acc[4][4];
    #pragma unroll
    for (int mt = 0; mt < 4; mt++)
        #pragma unroll
        for (int nt = 0; nt < 4; nt++) acc[mt][nt] = (f32x4){0.f, 0.f, 0.f, 0.f};

    #define GSTAGE(it_, p_)                                                             \
        {                                                                               \
            int k0_ = (it_) * 32;                                                       \
            _Pragma("unroll")                                                           \
            for (int j = 0; j < 2; j++) {                                               \
                int s = w * 128 + j * 64 + lane;                                        \
                int row = s >> 2, cl = s & 3;                                           \
                int c = cl ^ ((row >> 1) & 3);                                          \
                gload16(A  + (size_t)(m0 + row) * K + k0_ + c * 8,                      \
                        &Asl[p_][(size_t)(w * 128 + j * 64) * 8]);                      \
                gload16(Bt + (size_t)(n0 + row) * K + k0_ + c * 8,                      \
                        &Bsl[p_][(size_t)(w * 128 + j * 64) * 8]);                      \
            }                                                                           \
        }

    GSTAGE(0, 0)

    for (int it = 0; it < 32; it++) {
        const int p = it & 1;
        __syncthreads();                 // staging for it complete; buf !p free
        if (it + 1 < 32) GSTAGE(it + 1, (it + 1) & 1)

        bf16x8 af[4], bfr[4];
        #pragma unroll
        for (int mt = 0; mt < 4; mt++) {
            int row = wm * 64 + mt * 16 + l16;
            int cl = quad ^ ((row >> 1) & 3);
            af[mt] = *(const bf16x8*)&Asl[p][(row * 4 + cl) * 8];
        }
        #pragma unroll
        for (int nt = 0; nt < 4; nt++) {
            int row = wn * 64 + nt * 16 + l16;
            int cl = quad ^ ((row >> 1) & 3);
            bfr[nt] = *(const bf16x8*)&Bsl[p][(row * 4 + cl) * 8];
        }
        #pragma unroll
        for (int mt = 0; mt < 4; mt++)
            #pragma unroll
            for (int nt = 0; nt < 4; nt++)
                acc[mt][nt] = __builtin_amdgcn_mfma_f32_16x16x32_bf16(af[mt], bfr[nt], acc[mt][nt], 0, 0, 0);
    }

    if (mode == 0) {
        float* o = (float*)out0;
        #pragma unroll
        for (int nt = 0; nt < 4; nt++) {
            int col = n0 + wn * 64 + nt * 16 + l16;
            float bb = b0[col];
            #pragma unroll
            for (int mt = 0; mt < 4; mt++) {
                int mb = m0 + wm * 64 + mt * 16 + quad * 4;
                #pragma unroll
                for (int r = 0; r < 4; r++)
                    o[(size_t)(mb + r) * 1024 + col] = acc[mt][nt][r] + bb;
            }
        }
    } else {
        #pragma unroll
        for (int nt = 0; nt < 4; nt++) {
            int col = n0 + wn * 64 + nt * 16 + l16;
            int kind = col >> 10, cc = col & 1023;
            int h = cc >> 6, d = cc & 63;
            const float* bp = (kind == 0) ? b0 : (kind == 1) ? b1 : b2;
            float bb = bp[cc];
            #pragma unroll
            for (int mt = 0; mt < 4; mt++) {
                int m = m0 + wm * 64 + mt * 16 + quad * 4;
                int b = m >> 11, s = m & 2047;
                if (kind < 2) {
                    unsigned short* dst = ((kind == 0) ? (unsigned short*)out0 : out1) +
                        ((size_t)(b * NUM_HEADS + h) * S_LEN + s) * HEAD_DIM + d;
                    #pragma unroll
                    for (int r = 0; r < 4; r++)
                        dst[(size_t)r * HEAD_DIM] = f2bf(acc[mt][nt][r] + bb);
                } else {
                    unsigned int lo = pkrtz(acc[mt][nt][0] + bb, acc[mt][nt][1] + bb);
                    unsigned int hi = pkrtz(acc[mt][nt][2] + bb, acc[mt][nt][3] + bb);
                    *(uint2*)(out2 + ((size_t)(b * NUM_HEADS + h) * HEAD_DIM + d) * S_LEN + s) =
                        make_uint2(lo, hi);
                }
            }
        }
    }
}

// ---------------- MFMA flash attention, split-K(2), 24KB LDS / 6 blocks/CU ----------------
// Grid (NPH, 2). Single-buffered K/V in LDS; next chunk prefetched into registers.
__global__ __launch_bounds__(256, 6) void attn_kernel(
    const unsigned short* __restrict__ Q, const unsigned short* __restrict__ K,
    const unsigned short* __restrict__ Vtg, const int* __restrict__ work,
    unsigned short* __restrict__ opart, float* __restrict__ lpart)
{
    const int bx = blockIdx.x, half = blockIdx.y;
    const int pair = bx >> 4, h = bx & 15;
    const int tid  = threadIdx.x;
    const int w    = tid >> 6, lane = tid & 63;
    const int quad = lane >> 4, l16 = lane & 15;

    if (pair >= work[0]) return;                 // dropped: combine zero-fills
    const int e = work[1 + pair];
    const int b = e >> 5, qblk = e & 31;

    __shared__ unsigned short Kbuf[BS * HEAD_DIM];   // bf16, swizzled 16B chunks, 8KB
    __shared__ unsigned short Vbuf[HEAD_DIM * BS];   // fp16, swizzled 16B chunks, 8KB
    __shared__ unsigned short Pt[4][16 * 64];        // fp16 per-wave, 8KB

    const size_t bh = (size_t)(b * NUM_HEADS + h);
    const unsigned short* Kb = K + bh * S_LEN * HEAD_DIM + (size_t)half * 1024 * HEAD_DIM;
    const unsigned short* Vb = Vtg + bh * HEAD_DIM * S_LEN + (size_t)half * 1024;  // [dim][S]
    const unsigned short* Qb = Q + bh * S_LEN * HEAD_DIM;

    const int qrow = qblk * BS + w * 16 + l16;
    bf16x8 qf[2];
    #pragma unroll
    for (int ks = 0; ks < 2; ks++)
        qf[ks] = *(const bf16x8*)(Qb + (size_t)qrow * HEAD_DIM + ks * 32 + quad * 8);

    f32x4 o[4];
    #pragma unroll
    for (int mt = 0; mt < 4; mt++) o[mt] = (f32x4){0.f, 0.f, 0.f, 0.f};
    float l = 0.f;

    // staging slots: s = w*128 + {0,64} + lane; row = s>>3, swz chunk (s&7)^(row&7)
    const int sA = w * 128 + lane, sB = sA + 64;
    const int rA = sA >> 3, cA = (sA & 7) ^ (rA & 7);
    const int rB = sB >> 3, cB = (sB & 7) ^ (rB & 7);
    const size_t koA = (size_t)rA * HEAD_DIM + cA * 8, koB = (size_t)rB * HEAD_DIM + cB * 8;
    const size_t voA = (size_t)rA * S_LEN + cA * 8,    voB = (size_t)rB * S_LEN + cB * 8;

    uint4 kr0, kr1, vr0, vr1;
    #define LOADREGS(kc_)                                                       \
        {                                                                       \
            const unsigned short* kg_ = Kb + (size_t)(kc_) * BS * HEAD_DIM;     \
            const unsigned short* vg_ = Vb + (size_t)(kc_) * BS;                \
            kr0 = *(const uint4*)(kg_ + koA); kr1 = *(const uint4*)(kg_ + koB); \
            vr0 = *(const uint4*)(vg_ + voA); vr1 = *(const uint4*)(vg_ + voB); \
        }
    #define WRITELDS()                                                          \
        {                                                                       \
            *(uint4*)&Kbuf[(size_t)sA * 8] = kr0;                               \
            *(uint4*)&Kbuf[(size_t)sB * 8] = kr1;                               \
            *(uint4*)&Vbuf[(size_t)sA * 8] = vr0;                               \
            *(uint4*)&Vbuf[(size_t)sB * 8] = vr1;                               \
        }

    LOADREGS(0)
    WRITELDS()
    __syncthreads();

    for (int kc = 0; kc < 16; kc++) {
        if (kc + 1 < 16) LOADREGS(kc + 1)        // global latency hides under compute

        // S^T[key][qrow] = K · Q^T (bf16)
        f32x4 st[4];
        #pragma unroll
        for (int mt = 0; mt < 4; mt++) {
            f32x4 acc = {0.f, 0.f, 0.f, 0.f};
            #pragma unroll
            for (int ks = 0; ks < 2; ks++) {
                int kk = mt * 16 + l16;
                bf16x8 kf = *(const bf16x8*)&Kbuf[(size_t)(kk * 8 + ((ks * 4 + quad) ^ (kk & 7))) * 8];
                acc = __builtin_amdgcn_mfma_f32_16x16x32_bf16(kf, qf[ks], acc, 0, 0, 0);
            }
            st[mt] = acc;
        }

        // no-max softmax: p = exp2(score_raw * SCEXP)
        float pv[16], sum = 0.f;
        #pragma unroll
        for (int mt = 0; mt < 4; mt++)
            #pragma unroll
            for (int r = 0; r < 4; r++) {
                float ex = exp2f(st[mt][r] * SCEXP);
                pv[mt * 4 + r] = ex; sum += ex;
            }
        sum += __shfl_xor(sum, 16, 64);
        sum += __shfl_xor(sum, 32, 64);
        l += sum;

        // P^T -> Pt[w] fp16: row l16, 16B chunk index swizzled by ^(l16&7)
        #pragma unroll
        for (int mt = 0; mt < 4; mt++) {
            unsigned int lo = pkrtz(pv[mt * 4 + 0], pv[mt * 4 + 1]);
            unsigned int hi = pkrtz(pv[mt * 4 + 2], pv[mt * 4 + 3]);
            int c16 = 2 * mt + (quad >> 1);
            *(uint2*)&Pt[w][l16 * 64 + ((c16 ^ (l16 & 7)) * 8 + (quad & 1) * 4)] = make_uint2(lo, hi);
        }

        // O^T += V^T · P^T (fp16 MFMA)
        #pragma unroll
        for (int ks = 0; ks < 2; ks++) {
            f16x8 pf = *(const f16x8*)&Pt[w][l16 * 64 + (((4 * ks + quad) ^ (l16 & 7)) * 8)];
            #pragma unroll
            for (int mt = 0; mt < 4; mt++) {
                int d = mt * 16 + l16;
                f16x8 vf = *(const f16x8*)&Vbuf[(size_t)(d * 8 + ((ks * 4 + quad) ^ (d & 7))) * 8];
                o[mt] = __builtin_amdgcn_mfma_f32_16x16x32_f16(vf, pf, o[mt], 0, 0, 0);
            }
        }

        __syncthreads();                          // all waves done reading Kbuf/Vbuf
        if (kc + 1 < 16) {
            WRITELDS()                            // stage next chunk from registers
            __syncthreads();
        }
    }

    // partial epilogue: fp16 O^T dump (coalesced) + l
    unsigned short* ob = opart + ((size_t)(half * NPH + bx)) * 4096 + tid * 16;
    uint4 w0, w1;
    w0.x = pkrtz(o[0][0], o[0][1]); w0.y = pkrtz(o[0][2], o[0][3]);
    w0.z = pkrtz(o[1][0], o[1][1]); w0.w = pkrtz(o[1][2], o[1][3]);
    w1.x = pkrtz(o[2][0], o[2][1]); w1.y = pkrtz(o[2][2], o[2][3]);
    w1.z = pkrtz(o[3][0], o[3][1]); w1.w = pkrtz(o[3][2], o[3][3]);
    *(uint4*)ob = w0;
    *(uint4*)(ob + 8) = w1;
    if (quad == 0) lpart[(size_t)(half * NPH + bx) * 64 + w * 16 + l16] = l;
}

// ---------------- combine: sum halves, normalize, transpose, store bf16 ----------------
__global__ __launch_bounds__(256) void attn_combine(
    const unsigned short* __restrict__ opart, const float* __restrict__ lpart,
    const int* __restrict__ work, unsigned short* __restrict__ attn_out)
{
    const int bx = blockIdx.x;
    const int pair = bx >> 4, h = bx & 15;
    const int tid  = threadIdx.x;
    const int w    = tid >> 6, lane = tid & 63;
    const int quad = lane >> 4, l16 = lane & 15;

    const int e = work[1 + pair];
    const int b = e >> 5, qblk = e & 31;
    unsigned short* ablk = attn_out + ((size_t)(b * S_LEN + qblk * BS)) * D_MODEL + h * HEAD_DIM;

    if (pair >= work[0]) {                       // dropped: zero-fill
        uint4 z = make_uint4(0, 0, 0, 0);
        #pragma unroll
        for (int i = 0; i < 2; i++) {
            int u = tid + i * 256;
            int row = u >> 3, c8 = (u & 7) * 8;
            *(uint4*)(ablk + (size_t)row * D_MODEL + c8) = z;
        }
        return;
    }

    __shared__ float Obuf[4][HEAD_DIM * 17];

    const f16x8* p0 = (const f16x8*)(opart + (size_t)bx * 4096 + tid * 16);
    const f16x8* p1 = (const f16x8*)(opart + ((size_t)NPH + bx) * 4096 + tid * 16);
    f16x8 a0 = p0[0], a1 = p0[1], b0 = p1[0], b1 = p1[1];
    float lsum = lpart[(size_t)bx * 64 + w * 16 + l16] +
                 lpart[((size_t)NPH + bx) * 64 + w * 16 + l16];
    float inv = 1.0f / lsum;

    float osum[16];
    #pragma unroll
    for (int j = 0; j < 8; j++) {
        osum[j]     = (float)a0[j] + (float)b0[j];
        osum[8 + j] = (float)a1[j] + (float)b1[j];
    }
    #pragma unroll
    for (int mt = 0; mt < 4; mt++)
        #pragma unroll
        for (int r = 0; r < 4; r++)
            Obuf[w][(mt * 16 + quad * 4 + r) * 17 + l16] = osum[mt * 4 + r] * inv;
    // wave-private buffer: in-wave ordering via compiler waitcnts
    #pragma unroll
    for (int i = 0; i < 4; i++) {
        int uu = lane + 64 * i;
        int row = uu >> 4, d4 = (uu & 15) * 4;
        float x0 = Obuf[w][(d4 + 0) * 17 + row];
        float x1 = Obuf[w][(d4 + 1) * 17 + row];
        float x2 = Obuf[w][(d4 + 2) * 17 + row];
        float x3 = Obuf[w][(d4 + 3) * 17 + row];
        unsigned int lo = (unsigned int)f2bf(x0) | ((unsigned int)f2bf(x1) << 16);
        unsigned int hi = (unsigned int)f2bf(x2) | ((unsigned int)f2bf(x3) << 16);
        *(uint2*)(ablk + (size_t)(w * 16 + row) * D_MODEL + d4) = make_uint2(lo, hi);
    }
}

extern "C" void kernel_launch(void* const* d_in, const int* in_sizes, int n_in,
                              void* d_out, int out_size, void* d_ws, size_t ws_size,
                              hipStream_t stream) {
    const float* x  = (const float*)d_in[0];
    const float* G  = (const float*)d_in[1];
    const float* Wq = (const float*)d_in[2];
    const float* bq = (const float*)d_in[3];
    const float* Wk = (const float*)d_in[4];
    const float* bk = (const float*)d_in[5];
    const float* Wv = (const float*)d_in[6];
    const float* bv = (const float*)d_in[7];
    const float* Wo = (const float*)d_in[8];
    const float* bo = (const float*)d_in[9];
    float* out = (float*)d_out;

    char* wsp = (char*)d_ws;
    int* keep = (int*)wsp;                                           // 64 ints
    int* work = keep + 64;                                           // 65 ints
    unsigned short* xb    = (unsigned short*)(wsp + 1024);           // 4M elems bf16
    unsigned short* wcat  = xb + (size_t)M_ROWS * D_MODEL;           // 3M elems bf16
    unsigned short* wot   = wcat + (size_t)3 * 1024 * 1024;          // 1M elems bf16
    unsigned short* q     = wot + (size_t)1024 * 1024;               // bf16
    unsigned short* k     = q + QKV_ELEMS;                           // bf16
    unsigned short* vt    = k + QKV_ELEMS;                           // fp16 (transposed)
    unsigned short* attnb = vt + QKV_ELEMS;                          // bf16
    unsigned short* opart = attnb + (size_t)M_ROWS * D_MODEL;        // 2*NPH*4096 fp16 = 16 MB
    float* lpart = (float*)(opart + (size_t)2 * NPH * 4096);         // 2*NPH*64 fp32

    prep_kernel<<<3073, 256, 0, stream>>>(x, G, Wq, Wk, Wv, Wo, xb, wcat, wot, keep, work);

    // fused QKV: [4096 x 3072]
    mfma_gemm<<<dim3(3072 / 128, M_ROWS / 128), 256, 0, stream>>>(
        xb, wcat, bq, bk, bv, keep, (void*)q, k, vt, 1);

    attn_kernel<<<dim3(NPH, 2), 256, 0, stream>>>(q, k, vt, work, opart, lpart);
    attn_combine<<<NPH, 256, 0, stream>>>(opart, lpart, work, attnb);

    // output projection: [4096 x 1024]
    mfma_gemm<<<dim3(1024 / 128, M_ROWS / 128), 256, 0, stream>>>(
        attnb, wot, bo, nullptr, nullptr, keep, (void*)out, nullptr, nullptr, 0);
}

// Round 8
// 202.554 us; speedup vs baseline: 1.1208x; 1.1208x over previous
//
#include <hip/hip_runtime.h>
#include <math.h>

#define D_MODEL   1024
#define NUM_HEADS 16
#define HEAD_DIM  64
#define BS        64
#define NB        32
#define S_LEN     2048
#define BATCH     2
#define M_ROWS    (BATCH * S_LEN)  // 4096
#define THRESH    0.99f
#define SCEXP     0.18033688f      // 0.125 * log2(e): p = exp2(score_raw * SCEXP)
#define NPH       (BATCH * NB * NUM_HEADS)   // 1024 (pair,head) work items

typedef __attribute__((ext_vector_type(8))) short bf16x8;
typedef __attribute__((ext_vector_type(8))) _Float16 f16x8;
typedef __attribute__((ext_vector_type(2))) __fp16 fp16v2;   // native return type of cvt_pkrtz
typedef __attribute__((ext_vector_type(4))) float f32x4;

static constexpr size_t QKV_ELEMS = (size_t)BATCH * NUM_HEADS * S_LEN * HEAD_DIM; // 4 Mi elems

__device__ __forceinline__ unsigned short f2bf(float f) {
    unsigned int u = __float_as_uint(f);
    u += 0x7fff + ((u >> 16) & 1);   // RNE
    return (unsigned short)(u >> 16);
}

__device__ __forceinline__ unsigned int pkrtz(float a, float b) {
    fp16v2 r = __builtin_amdgcn_cvt_pkrtz(a, b);   // v_cvt_pkrtz_f16_f32, 1 instr
    return __builtin_bit_cast(unsigned int, r);
}

// async global->LDS, 16B per lane; lds dest = wave-uniform base + lane*16
__device__ __forceinline__ void gload16(const void* gptr, void* lptr) {
    __builtin_amdgcn_global_load_lds(
        (const __attribute__((address_space(1))) void*)gptr,
        (__attribute__((address_space(3))) void*)lptr, 16, 0, 0);
}

// ---------------- fused prep: convert_x | transpose_w | compact ----------------
// blocks [0,2048): x fp32->bf16 ; [2048,3072): W transpose ; [3072]: keep+worklist
__global__ __launch_bounds__(256) void prep_kernel(
    const float* __restrict__ x, const float* __restrict__ G,
    const float* __restrict__ Wq, const float* __restrict__ Wk,
    const float* __restrict__ Wv, const float* __restrict__ Wo,
    unsigned short* __restrict__ xb, unsigned short* __restrict__ wcat,
    unsigned short* __restrict__ wot, int* __restrict__ keep, int* __restrict__ work)
{
    const int bid = blockIdx.x, tid = threadIdx.x;
    __shared__ float T[64][65];

    if (bid < 2048) {                       // ---- convert x ----
        size_t i = ((size_t)bid * 256 + tid) * 8;
        float4 a = *(const float4*)(x + i);
        float4 b = *(const float4*)(x + i + 4);
        uint4 o;
        o.x = (unsigned int)f2bf(a.x) | ((unsigned int)f2bf(a.y) << 16);
        o.y = (unsigned int)f2bf(a.z) | ((unsigned int)f2bf(a.w) << 16);
        o.z = (unsigned int)f2bf(b.x) | ((unsigned int)f2bf(b.y) << 16);
        o.w = (unsigned int)f2bf(b.z) | ((unsigned int)f2bf(b.w) << 16);
        *(uint4*)(xb + i) = o;
    } else if (bid < 3072) {                // ---- transpose W ----
        int i = bid - 2048;
        int mat = i >> 8, rem = i & 255;
        int k0 = (rem & 15) * 64, n0 = (rem >> 4) * 64;
        const float* W = (mat == 0) ? Wq : (mat == 1) ? Wk : (mat == 2) ? Wv : Wo;
        int rr = tid >> 4, c4 = (tid & 15) * 4;
        #pragma unroll
        for (int j = 0; j < 4; j++) {
            int row = rr + j * 16;
            float4 v = *(const float4*)(W + (size_t)(k0 + row) * 1024 + n0 + c4);
            T[row][c4 + 0] = v.x; T[row][c4 + 1] = v.y;
            T[row][c4 + 2] = v.z; T[row][c4 + 3] = v.w;
        }
        __syncthreads();
        unsigned short* dst = (mat < 3) ? (wcat + (size_t)mat * 1024 * 1024) : wot;
        #pragma unroll
        for (int j = 0; j < 4; j++) {
            int n = rr + j * 16;
            unsigned int lo = (unsigned int)f2bf(T[c4 + 0][n]) | ((unsigned int)f2bf(T[c4 + 1][n]) << 16);
            unsigned int hi = (unsigned int)f2bf(T[c4 + 2][n]) | ((unsigned int)f2bf(T[c4 + 3][n]) << 16);
            *(uint2*)(dst + (size_t)(n0 + n) * 1024 + k0 + c4) = make_uint2(lo, hi);
        }
    } else {                                // ---- compact (wave 0 only) ----
        if (tid < 64) {
            int t = tid;
            const float4* g = (const float4*)(G + (size_t)t * 64);
            float mx = 0.f;
            #pragma unroll
            for (int j = 0; j < 16; j++) {
                float4 v = g[j];
                mx = fmaxf(mx, fmaxf(fmaxf(fabsf(v.x), fabsf(v.y)), fmaxf(fabsf(v.z), fabsf(v.w))));
            }
            bool k = (mx >= THRESH);
            unsigned long long bal = __ballot(k);
            int nk = __popcll(bal);
            unsigned long long below = bal & ((1ull << t) - 1ull);
            int nbelow = (int)__popcll(below);
            keep[t] = k ? 1 : 0;
            if (t == 0) work[0] = nk;
            int pos = k ? nbelow : (nk + t - nbelow);
            work[1 + pos] = t;
        }
    }
}

// ---------------- bf16 MFMA GEMM (double-buffered): C = A[M][1024] @ Bt[N][1024]^T ----------------
// mode 0: fp32 out0 + b0; dropped tiles write bias rows.
// mode 1: fused QKV. kind 0->q(bf16), 1->k(bf16), 2->V^T(fp16, transposed global layout).
__global__ __launch_bounds__(256) void mfma_gemm(
    const unsigned short* __restrict__ A, const unsigned short* __restrict__ Bt,
    const float* __restrict__ b0, const float* __restrict__ b1, const float* __restrict__ b2,
    const int* __restrict__ keep,
    void* __restrict__ out0, unsigned short* __restrict__ out1, unsigned short* __restrict__ out2,
    int mode)
{
    const int K = 1024;
    const int n0 = blockIdx.x * 128, m0 = blockIdx.y * 128;
    const int tid = threadIdx.x, w = tid >> 6, lane = tid & 63;
    const int quad = lane >> 4, l16 = lane & 15;
    const int wm = w >> 1, wn = w & 1;

    const int kb0 = m0 >> 6;
    const bool dropped = (!keep[kb0]) && (!keep[kb0 + 1]);

    if (mode == 1 && (n0 >> 10) == 0 && dropped) return;
    if (mode == 0 && dropped) {
        float* o = (float*)out0;
        #pragma unroll
        for (int i = 0; i < 16; i++) {
            int u = tid + i * 256;
            int row = u >> 5, c = (u & 31) * 4;
            *(float4*)(o + (size_t)(m0 + row) * 1024 + n0 + c) = *(const float4*)(b0 + n0 + c);
        }
        return;
    }

    __shared__ unsigned short Asl[2][128 * 32];
    __shared__ unsigned short Bsl[2][128 * 32];

    f32x4 acc[4][4];
    #pragma unroll
    for (int mt = 0; mt < 4; mt++)
        #pragma unroll
        for (int nt = 0; nt < 4; nt++) acc[mt][nt] = (f32x4){0.f, 0.f, 0.f, 0.f};

    #define GSTAGE(it_, p_)                                                             \
        {                                                                               \
            int k0_ = (it_) * 32;                                                       \
            _Pragma("unroll")                                                           \
            for (int j = 0; j < 2; j++) {                                               \
                int s = w * 128 + j * 64 + lane;                                        \
                int row = s >> 2, cl = s & 3;                                           \
                int c = cl ^ ((row >> 1) & 3);                                          \
                gload16(A  + (size_t)(m0 + row) * K + k0_ + c * 8,                      \
                        &Asl[p_][(size_t)(w * 128 + j * 64) * 8]);                      \
                gload16(Bt + (size_t)(n0 + row) * K + k0_ + c * 8,                      \
                        &Bsl[p_][(size_t)(w * 128 + j * 64) * 8]);                      \
            }                                                                           \
        }

    GSTAGE(0, 0)

    for (int it = 0; it < 32; it++) {
        const int p = it & 1;
        __syncthreads();                 // staging for it complete; buf !p free
        if (it + 1 < 32) GSTAGE(it + 1, (it + 1) & 1)

        bf16x8 af[4], bfr[4];
        #pragma unroll
        for (int mt = 0; mt < 4; mt++) {
            int row = wm * 64 + mt * 16 + l16;
            int cl = quad ^ ((row >> 1) & 3);
            af[mt] = *(const bf16x8*)&Asl[p][(row * 4 + cl) * 8];
        }
        #pragma unroll
        for (int nt = 0; nt < 4; nt++) {
            int row = wn * 64 + nt * 16 + l16;
            int cl = quad ^ ((row >> 1) & 3);
            bfr[nt] = *(const bf16x8*)&Bsl[p][(row * 4 + cl) * 8];
        }
        #pragma unroll
        for (int mt = 0; mt < 4; mt++)
            #pragma unroll
            for (int nt = 0; nt < 4; nt++)
                acc[mt][nt] = __builtin_amdgcn_mfma_f32_16x16x32_bf16(af[mt], bfr[nt], acc[mt][nt], 0, 0, 0);
    }

    if (mode == 0) {
        float* o = (float*)out0;
        #pragma unroll
        for (int nt = 0; nt < 4; nt++) {
            int col = n0 + wn * 64 + nt * 16 + l16;
            float bb = b0[col];
            #pragma unroll
            for (int mt = 0; mt < 4; mt++) {
                int mb = m0 + wm * 64 + mt * 16 + quad * 4;
                #pragma unroll
                for (int r = 0; r < 4; r++)
                    o[(size_t)(mb + r) * 1024 + col] = acc[mt][nt][r] + bb;
            }
        }
    } else {
        #pragma unroll
        for (int nt = 0; nt < 4; nt++) {
            int col = n0 + wn * 64 + nt * 16 + l16;
            int kind = col >> 10, cc = col & 1023;
            int h = cc >> 6, d = cc & 63;
            const float* bp = (kind == 0) ? b0 : (kind == 1) ? b1 : b2;
            float bb = bp[cc];
            #pragma unroll
            for (int mt = 0; mt < 4; mt++) {
                int m = m0 + wm * 64 + mt * 16 + quad * 4;
                int b = m >> 11, s = m & 2047;
                if (kind < 2) {
                    unsigned short* dst = ((kind == 0) ? (unsigned short*)out0 : out1) +
                        ((size_t)(b * NUM_HEADS + h) * S_LEN + s) * HEAD_DIM + d;
                    #pragma unroll
                    for (int r = 0; r < 4; r++)
                        dst[(size_t)r * HEAD_DIM] = f2bf(acc[mt][nt][r] + bb);
                } else {
                    unsigned int lo = pkrtz(acc[mt][nt][0] + bb, acc[mt][nt][1] + bb);
                    unsigned int hi = pkrtz(acc[mt][nt][2] + bb, acc[mt][nt][3] + bb);
                    *(uint2*)(out2 + ((size_t)(b * NUM_HEADS + h) * HEAD_DIM + d) * S_LEN + s) =
                        make_uint2(lo, hi);
                }
            }
        }
    }
}

// ---------------- MFMA flash attention, split-K(2), 24KB LDS ----------------
// Grid (NPH, 2). Single-buffered K/V in LDS; next chunk prefetched into REGISTERS.
// launch_bounds(256,4): VGPR cap 128 -> no spill (r7's (256,6) capped at ~85 and
// spilled the prefetch regs to scratch: VGPR=40, WRITE_SIZE 3x). Occupancy is
// LDS-limited at 24KB -> 6 blocks/CU regardless of the min-waves declaration.
__global__ __launch_bounds__(256, 4) void attn_kernel(
    const unsigned short* __restrict__ Q, const unsigned short* __restrict__ K,
    const unsigned short* __restrict__ Vtg, const int* __restrict__ work,
    unsigned short* __restrict__ opart, float* __restrict__ lpart)
{
    const int bx = blockIdx.x, half = blockIdx.y;
    const int pair = bx >> 4, h = bx & 15;
    const int tid  = threadIdx.x;
    const int w    = tid >> 6, lane = tid & 63;
    const int quad = lane >> 4, l16 = lane & 15;

    if (pair >= work[0]) return;                 // dropped: combine zero-fills
    const int e = work[1 + pair];
    const int b = e >> 5, qblk = e & 31;

    __shared__ unsigned short Kbuf[BS * HEAD_DIM];   // bf16, swizzled 16B chunks, 8KB
    __shared__ unsigned short Vbuf[HEAD_DIM * BS];   // fp16, swizzled 16B chunks, 8KB
    __shared__ unsigned short Pt[4][16 * 64];        // fp16 per-wave, 8KB

    const size_t bh = (size_t)(b * NUM_HEADS + h);
    const unsigned short* Kb = K + bh * S_LEN * HEAD_DIM + (size_t)half * 1024 * HEAD_DIM;
    const unsigned short* Vb = Vtg + bh * HEAD_DIM * S_LEN + (size_t)half * 1024;  // [dim][S]
    const unsigned short* Qb = Q + bh * S_LEN * HEAD_DIM;

    const int qrow = qblk * BS + w * 16 + l16;
    bf16x8 qf[2];
    #pragma unroll
    for (int ks = 0; ks < 2; ks++)
        qf[ks] = *(const bf16x8*)(Qb + (size_t)qrow * HEAD_DIM + ks * 32 + quad * 8);

    f32x4 o[4];
    #pragma unroll
    for (int mt = 0; mt < 4; mt++) o[mt] = (f32x4){0.f, 0.f, 0.f, 0.f};
    float l = 0.f;

    // staging slots: s = w*128 + {0,64} + lane; row = s>>3, swz chunk (s&7)^(row&7)
    const int sA = w * 128 + lane, sB = sA + 64;
    const int rA = sA >> 3, cA = (sA & 7) ^ (rA & 7);
    const int rB = sB >> 3, cB = (sB & 7) ^ (rB & 7);
    const size_t koA = (size_t)rA * HEAD_DIM + cA * 8, koB = (size_t)rB * HEAD_DIM + cB * 8;
    const size_t voA = (size_t)rA * S_LEN + cA * 8,    voB = (size_t)rB * S_LEN + cB * 8;

    uint4 kr0, kr1, vr0, vr1;
    #define LOADREGS(kc_)                                                       \
        {                                                                       \
            const unsigned short* kg_ = Kb + (size_t)(kc_) * BS * HEAD_DIM;     \
            const unsigned short* vg_ = Vb + (size_t)(kc_) * BS;                \
            kr0 = *(const uint4*)(kg_ + koA); kr1 = *(const uint4*)(kg_ + koB); \
            vr0 = *(const uint4*)(vg_ + voA); vr1 = *(const uint4*)(vg_ + voB); \
        }
    #define WRITELDS()                                                          \
        {                                                                       \
            *(uint4*)&Kbuf[(size_t)sA * 8] = kr0;                               \
            *(uint4*)&Kbuf[(size_t)sB * 8] = kr1;                               \
            *(uint4*)&Vbuf[(size_t)sA * 8] = vr0;                               \
            *(uint4*)&Vbuf[(size_t)sB * 8] = vr1;                               \
        }

    LOADREGS(0)
    WRITELDS()
    __syncthreads();

    for (int kc = 0; kc < 16; kc++) {
        if (kc + 1 < 16) LOADREGS(kc + 1)        // global latency hides under compute

        // S^T[key][qrow] = K · Q^T (bf16)
        f32x4 st[4];
        #pragma unroll
        for (int mt = 0; mt < 4; mt++) {
            f32x4 acc = {0.f, 0.f, 0.f, 0.f};
            #pragma unroll
            for (int ks = 0; ks < 2; ks++) {
                int kk = mt * 16 + l16;
                bf16x8 kf = *(const bf16x8*)&Kbuf[(size_t)(kk * 8 + ((ks * 4 + quad) ^ (kk & 7))) * 8];
                acc = __builtin_amdgcn_mfma_f32_16x16x32_bf16(kf, qf[ks], acc, 0, 0, 0);
            }
            st[mt] = acc;
        }

        // no-max softmax: p = exp2(score_raw * SCEXP)
        float pv[16], sum = 0.f;
        #pragma unroll
        for (int mt = 0; mt < 4; mt++)
            #pragma unroll
            for (int r = 0; r < 4; r++) {
                float ex = exp2f(st[mt][r] * SCEXP);
                pv[mt * 4 + r] = ex; sum += ex;
            }
        sum += __shfl_xor(sum, 16, 64);
        sum += __shfl_xor(sum, 32, 64);
        l += sum;

        // P^T -> Pt[w] fp16: row l16, 16B chunk index swizzled by ^(l16&7)
        #pragma unroll
        for (int mt = 0; mt < 4; mt++) {
            unsigned int lo = pkrtz(pv[mt * 4 + 0], pv[mt * 4 + 1]);
            unsigned int hi = pkrtz(pv[mt * 4 + 2], pv[mt * 4 + 3]);
            int c16 = 2 * mt + (quad >> 1);
            *(uint2*)&Pt[w][l16 * 64 + ((c16 ^ (l16 & 7)) * 8 + (quad & 1) * 4)] = make_uint2(lo, hi);
        }

        // O^T += V^T · P^T (fp16 MFMA)
        #pragma unroll
        for (int ks = 0; ks < 2; ks++) {
            f16x8 pf = *(const f16x8*)&Pt[w][l16 * 64 + (((4 * ks + quad) ^ (l16 & 7)) * 8)];
            #pragma unroll
            for (int mt = 0; mt < 4; mt++) {
                int d = mt * 16 + l16;
                f16x8 vf = *(const f16x8*)&Vbuf[(size_t)(d * 8 + ((ks * 4 + quad) ^ (d & 7))) * 8];
                o[mt] = __builtin_amdgcn_mfma_f32_16x16x32_f16(vf, pf, o[mt], 0, 0, 0);
            }
        }

        __syncthreads();                          // all waves done reading Kbuf/Vbuf
        if (kc + 1 < 16) {
            WRITELDS()                            // stage next chunk from registers
            __syncthreads();
        }
    }

    // partial epilogue: fp16 O^T dump (coalesced) + l
    unsigned short* ob = opart + ((size_t)(half * NPH + bx)) * 4096 + tid * 16;
    uint4 w0, w1;
    w0.x = pkrtz(o[0][0], o[0][1]); w0.y = pkrtz(o[0][2], o[0][3]);
    w0.z = pkrtz(o[1][0], o[1][1]); w0.w = pkrtz(o[1][2], o[1][3]);
    w1.x = pkrtz(o[2][0], o[2][1]); w1.y = pkrtz(o[2][2], o[2][3]);
    w1.z = pkrtz(o[3][0], o[3][1]); w1.w = pkrtz(o[3][2], o[3][3]);
    *(uint4*)ob = w0;
    *(uint4*)(ob + 8) = w1;
    if (quad == 0) lpart[(size_t)(half * NPH + bx) * 64 + w * 16 + l16] = l;
}

// ---------------- combine: sum halves, normalize, transpose, store bf16 ----------------
__global__ __launch_bounds__(256) void attn_combine(
    const unsigned short* __restrict__ opart, const float* __restrict__ lpart,
    const int* __restrict__ work, unsigned short* __restrict__ attn_out)
{
    const int bx = blockIdx.x;
    const int pair = bx >> 4, h = bx & 15;
    const int tid  = threadIdx.x;
    const int w    = tid >> 6, lane = tid & 63;
    const int quad = lane >> 4, l16 = lane & 15;

    const int e = work[1 + pair];
    const int b = e >> 5, qblk = e & 31;
    unsigned short* ablk = attn_out + ((size_t)(b * S_LEN + qblk * BS)) * D_MODEL + h * HEAD_DIM;

    if (pair >= work[0]) {                       // dropped: zero-fill
        uint4 z = make_uint4(0, 0, 0, 0);
        #pragma unroll
        for (int i = 0; i < 2; i++) {
            int u = tid + i * 256;
            int row = u >> 3, c8 = (u & 7) * 8;
            *(uint4*)(ablk + (size_t)row * D_MODEL + c8) = z;
        }
        return;
    }

    __shared__ float Obuf[4][HEAD_DIM * 17];

    const f16x8* p0 = (const f16x8*)(opart + (size_t)bx * 4096 + tid * 16);
    const f16x8* p1 = (const f16x8*)(opart + ((size_t)NPH + bx) * 4096 + tid * 16);
    f16x8 a0 = p0[0], a1 = p0[1], b0 = p1[0], b1 = p1[1];
    float lsum = lpart[(size_t)bx * 64 + w * 16 + l16] +
                 lpart[((size_t)NPH + bx) * 64 + w * 16 + l16];
    float inv = 1.0f / lsum;

    float osum[16];
    #pragma unroll
    for (int j = 0; j < 8; j++) {
        osum[j]     = (float)a0[j] + (float)b0[j];
        osum[8 + j] = (float)a1[j] + (float)b1[j];
    }
    #pragma unroll
    for (int mt = 0; mt < 4; mt++)
        #pragma unroll
        for (int r = 0; r < 4; r++)
            Obuf[w][(mt * 16 + quad * 4 + r) * 17 + l16] = osum[mt * 4 + r] * inv;
    // wave-private buffer: in-wave ordering via compiler waitcnts
    #pragma unroll
    for (int i = 0; i < 4; i++) {
        int uu = lane + 64 * i;
        int row = uu >> 4, d4 = (uu & 15) * 4;
        float x0 = Obuf[w][(d4 + 0) * 17 + row];
        float x1 = Obuf[w][(d4 + 1) * 17 + row];
        float x2 = Obuf[w][(d4 + 2) * 17 + row];
        float x3 = Obuf[w][(d4 + 3) * 17 + row];
        unsigned int lo = (unsigned int)f2bf(x0) | ((unsigned int)f2bf(x1) << 16);
        unsigned int hi = (unsigned int)f2bf(x2) | ((unsigned int)f2bf(x3) << 16);
        *(uint2*)(ablk + (size_t)(w * 16 + row) * D_MODEL + d4) = make_uint2(lo, hi);
    }
}

extern "C" void kernel_launch(void* const* d_in, const int* in_sizes, int n_in,
                              void* d_out, int out_size, void* d_ws, size_t ws_size,
                              hipStream_t stream) {
    const float* x  = (const float*)d_in[0];
    const float* G  = (const float*)d_in[1];
    const float* Wq = (const float*)d_in[2];
    const float* bq = (const float*)d_in[3];
    const float* Wk = (const float*)d_in[4];
    const float* bk = (const float*)d_in[5];
    const float* Wv = (const float*)d_in[6];
    const float* bv = (const float*)d_in[7];
    const float* Wo = (const float*)d_in[8];
    const float* bo = (const float*)d_in[9];
    float* out = (float*)d_out;

    char* wsp = (char*)d_ws;
    int* keep = (int*)wsp;                                           // 64 ints
    int* work = keep + 64;                                           // 65 ints
    unsigned short* xb    = (unsigned short*)(wsp + 1024);           // 4M elems bf16
    unsigned short* wcat  = xb + (size_t)M_ROWS * D_MODEL;           // 3M elems bf16
    unsigned short* wot   = wcat + (size_t)3 * 1024 * 1024;          // 1M elems bf16
    unsigned short* q     = wot + (size_t)1024 * 1024;               // bf16
    unsigned short* k     = q + QKV_ELEMS;                           // bf16
    unsigned short* vt    = k + QKV_ELEMS;                           // fp16 (transposed)
    unsigned short* attnb = vt + QKV_ELEMS;                          // bf16
    unsigned short* opart = attnb + (size_t)M_ROWS * D_MODEL;        // 2*NPH*4096 fp16 = 16 MB
    float* lpart = (float*)(opart + (size_t)2 * NPH * 4096);         // 2*NPH*64 fp32

    prep_kernel<<<3073, 256, 0, stream>>>(x, G, Wq, Wk, Wv, Wo, xb, wcat, wot, keep, work);

    // fused QKV: [4096 x 3072]
    mfma_gemm<<<dim3(3072 / 128, M_ROWS / 128), 256, 0, stream>>>(
        xb, wcat, bq, bk, bv, keep, (void*)q, k, vt, 1);

    attn_kernel<<<dim3(NPH, 2), 256, 0, stream>>>(q, k, vt, work, opart, lpart);
    attn_combine<<<NPH, 256, 0, stream>>>(opart, lpart, work, attnb);

    // output projection: [4096 x 1024]
    mfma_gemm<<<dim3(1024 / 128, M_ROWS / 128), 256, 0, stream>>>(
        attnb, wot, bo, nullptr, nullptr, keep, (void*)out, nullptr, nullptr, 0);
}

// Round 9
// 197.532 us; speedup vs baseline: 1.1493x; 1.0254x over previous
//
#include <hip/hip_runtime.h>
#include <math.h>

#define D_MODEL   1024
#define NUM_HEADS 16
#define HEAD_DIM  64
#define BS        64
#define NB        32
#define S_LEN     2048
#define BATCH     2
#define M_ROWS    (BATCH * S_LEN)  // 4096
#define THRESH    0.99f
#define SCEXP     0.18033688f      // 0.125 * log2(e); folded into q at QKV epilogue
#define NPH       (BATCH * NB * NUM_HEADS)   // 1024 (pair,head) work items
#define SPLITK    4                          // key-range split for attention

typedef __attribute__((ext_vector_type(8))) short bf16x8;
typedef __attribute__((ext_vector_type(8))) _Float16 f16x8;
typedef __attribute__((ext_vector_type(2))) __fp16 fp16v2;   // native return type of cvt_pkrtz
typedef __attribute__((ext_vector_type(4))) float f32x4;

static constexpr size_t QKV_ELEMS = (size_t)BATCH * NUM_HEADS * S_LEN * HEAD_DIM; // 4 Mi elems

__device__ __forceinline__ unsigned short f2bf(float f) {
    unsigned int u = __float_as_uint(f);
    u += 0x7fff + ((u >> 16) & 1);   // RNE
    return (unsigned short)(u >> 16);
}

__device__ __forceinline__ unsigned int pkrtz(float a, float b) {
    fp16v2 r = __builtin_amdgcn_cvt_pkrtz(a, b);   // v_cvt_pkrtz_f16_f32, 1 instr
    return __builtin_bit_cast(unsigned int, r);
}

// async global->LDS, 16B per lane; lds dest = wave-uniform base + lane*16
__device__ __forceinline__ void gload16(const void* gptr, void* lptr) {
    __builtin_amdgcn_global_load_lds(
        (const __attribute__((address_space(1))) void*)gptr,
        (__attribute__((address_space(3))) void*)lptr, 16, 0, 0);
}

// ---------------- fused prep: convert_x | transpose_w | compact ----------------
// blocks [0,2048): x fp32->bf16 ; [2048,3072): W transpose ; [3072]: keep+worklist
__global__ __launch_bounds__(256) void prep_kernel(
    const float* __restrict__ x, const float* __restrict__ G,
    const float* __restrict__ Wq, const float* __restrict__ Wk,
    const float* __restrict__ Wv, const float* __restrict__ Wo,
    unsigned short* __restrict__ xb, unsigned short* __restrict__ wcat,
    unsigned short* __restrict__ wot, int* __restrict__ keep, int* __restrict__ work)
{
    const int bid = blockIdx.x, tid = threadIdx.x;
    __shared__ float T[64][65];

    if (bid < 2048) {                       // ---- convert x ----
        size_t i = ((size_t)bid * 256 + tid) * 8;
        float4 a = *(const float4*)(x + i);
        float4 b = *(const float4*)(x + i + 4);
        uint4 o;
        o.x = (unsigned int)f2bf(a.x) | ((unsigned int)f2bf(a.y) << 16);
        o.y = (unsigned int)f2bf(a.z) | ((unsigned int)f2bf(a.w) << 16);
        o.z = (unsigned int)f2bf(b.x) | ((unsigned int)f2bf(b.y) << 16);
        o.w = (unsigned int)f2bf(b.z) | ((unsigned int)f2bf(b.w) << 16);
        *(uint4*)(xb + i) = o;
    } else if (bid < 3072) {                // ---- transpose W ----
        int i = bid - 2048;
        int mat = i >> 8, rem = i & 255;
        int k0 = (rem & 15) * 64, n0 = (rem >> 4) * 64;
        const float* W = (mat == 0) ? Wq : (mat == 1) ? Wk : (mat == 2) ? Wv : Wo;
        int rr = tid >> 4, c4 = (tid & 15) * 4;
        #pragma unroll
        for (int j = 0; j < 4; j++) {
            int row = rr + j * 16;
            float4 v = *(const float4*)(W + (size_t)(k0 + row) * 1024 + n0 + c4);
            T[row][c4 + 0] = v.x; T[row][c4 + 1] = v.y;
            T[row][c4 + 2] = v.z; T[row][c4 + 3] = v.w;
        }
        __syncthreads();
        unsigned short* dst = (mat < 3) ? (wcat + (size_t)mat * 1024 * 1024) : wot;
        #pragma unroll
        for (int j = 0; j < 4; j++) {
            int n = rr + j * 16;
            unsigned int lo = (unsigned int)f2bf(T[c4 + 0][n]) | ((unsigned int)f2bf(T[c4 + 1][n]) << 16);
            unsigned int hi = (unsigned int)f2bf(T[c4 + 2][n]) | ((unsigned int)f2bf(T[c4 + 3][n]) << 16);
            *(uint2*)(dst + (size_t)(n0 + n) * 1024 + k0 + c4) = make_uint2(lo, hi);
        }
    } else {                                // ---- compact (wave 0 only) ----
        if (tid < 64) {
            int t = tid;
            const float4* g = (const float4*)(G + (size_t)t * 64);
            float mx = 0.f;
            #pragma unroll
            for (int j = 0; j < 16; j++) {
                float4 v = g[j];
                mx = fmaxf(mx, fmaxf(fmaxf(fabsf(v.x), fabsf(v.y)), fmaxf(fabsf(v.z), fabsf(v.w))));
            }
            bool k = (mx >= THRESH);
            unsigned long long bal = __ballot(k);
            int nk = __popcll(bal);
            unsigned long long below = bal & ((1ull << t) - 1ull);
            int nbelow = (int)__popcll(below);
            keep[t] = k ? 1 : 0;
            if (t == 0) work[0] = nk;
            int pos = k ? nbelow : (nk + t - nbelow);
            work[1 + pos] = t;
        }
    }
}

// ---------------- bf16 MFMA GEMM (double-buffered): C = A[M][1024] @ Bt[N][1024]^T ----------------
// mode 0: fp32 out0 + b0; dropped tiles write bias rows.
// mode 1: fused QKV. kind 0->q(bf16, pre-scaled by SCEXP), 1->k(bf16), 2->V^T(fp16, transposed).
__global__ __launch_bounds__(256) void mfma_gemm(
    const unsigned short* __restrict__ A, const unsigned short* __restrict__ Bt,
    const float* __restrict__ b0, const float* __restrict__ b1, const float* __restrict__ b2,
    const int* __restrict__ keep,
    void* __restrict__ out0, unsigned short* __restrict__ out1, unsigned short* __restrict__ out2,
    int mode)
{
    const int K = 1024;
    const int n0 = blockIdx.x * 128, m0 = blockIdx.y * 128;
    const int tid = threadIdx.x, w = tid >> 6, lane = tid & 63;
    const int quad = lane >> 4, l16 = lane & 15;
    const int wm = w >> 1, wn = w & 1;

    const int kb0 = m0 >> 6;
    const bool dropped = (!keep[kb0]) && (!keep[kb0 + 1]);

    if (mode == 1 && (n0 >> 10) == 0 && dropped) return;
    if (mode == 0 && dropped) {
        float* o = (float*)out0;
        #pragma unroll
        for (int i = 0; i < 16; i++) {
            int u = tid + i * 256;
            int row = u >> 5, c = (u & 31) * 4;
            *(float4*)(o + (size_t)(m0 + row) * 1024 + n0 + c) = *(const float4*)(b0 + n0 + c);
        }
        return;
    }

    __shared__ unsigned short Asl[2][128 * 32];
    __shared__ unsigned short Bsl[2][128 * 32];

    f32x4 acc[4][4];
    #pragma unroll
    for (int mt = 0; mt < 4; mt++)
        #pragma unroll
        for (int nt = 0; nt < 4; nt++) acc[mt][nt] = (f32x4){0.f, 0.f, 0.f, 0.f};

    #define GSTAGE(it_, p_)                                                             \
        {                                                                               \
            int k0_ = (it_) * 32;                                                       \
            _Pragma("unroll")                                                           \
            for (int j = 0; j < 2; j++) {                                               \
                int s = w * 128 + j * 64 + lane;                                        \
                int row = s >> 2, cl = s & 3;                                           \
                int c = cl ^ ((row >> 1) & 3);                                          \
                gload16(A  + (size_t)(m0 + row) * K + k0_ + c * 8,                      \
                        &Asl[p_][(size_t)(w * 128 + j * 64) * 8]);                      \
                gload16(Bt + (size_t)(n0 + row) * K + k0_ + c * 8,                      \
                        &Bsl[p_][(size_t)(w * 128 + j * 64) * 8]);                      \
            }                                                                           \
        }

    GSTAGE(0, 0)

    for (int it = 0; it < 32; it++) {
        const int p = it & 1;
        __syncthreads();                 // staging for it complete; buf !p free
        if (it + 1 < 32) GSTAGE(it + 1, (it + 1) & 1)

        bf16x8 af[4], bfr[4];
        #pragma unroll
        for (int mt = 0; mt < 4; mt++) {
            int row = wm * 64 + mt * 16 + l16;
            int cl = quad ^ ((row >> 1) & 3);
            af[mt] = *(const bf16x8*)&Asl[p][(row * 4 + cl) * 8];
        }
        #pragma unroll
        for (int nt = 0; nt < 4; nt++) {
            int row = wn * 64 + nt * 16 + l16;
            int cl = quad ^ ((row >> 1) & 3);
            bfr[nt] = *(const bf16x8*)&Bsl[p][(row * 4 + cl) * 8];
        }
        #pragma unroll
        for (int mt = 0; mt < 4; mt++)
            #pragma unroll
            for (int nt = 0; nt < 4; nt++)
                acc[mt][nt] = __builtin_amdgcn_mfma_f32_16x16x32_bf16(af[mt], bfr[nt], acc[mt][nt], 0, 0, 0);
    }

    if (mode == 0) {
        float* o = (float*)out0;
        #pragma unroll
        for (int nt = 0; nt < 4; nt++) {
            int col = n0 + wn * 64 + nt * 16 + l16;
            float bb = b0[col];
            #pragma unroll
            for (int mt = 0; mt < 4; mt++) {
                int mb = m0 + wm * 64 + mt * 16 + quad * 4;
                #pragma unroll
                for (int r = 0; r < 4; r++)
                    o[(size_t)(mb + r) * 1024 + col] = acc[mt][nt][r] + bb;
            }
        }
    } else {
        #pragma unroll
        for (int nt = 0; nt < 4; nt++) {
            int col = n0 + wn * 64 + nt * 16 + l16;
            int kind = col >> 10, cc = col & 1023;
            int h = cc >> 6, d = cc & 63;
            const float* bp = (kind == 0) ? b0 : (kind == 1) ? b1 : b2;
            float bb = bp[cc];
            #pragma unroll
            for (int mt = 0; mt < 4; mt++) {
                int m = m0 + wm * 64 + mt * 16 + quad * 4;
                int b = m >> 11, s = m & 2047;
                if (kind < 2) {
                    unsigned short* dst = ((kind == 0) ? (unsigned short*)out0 : out1) +
                        ((size_t)(b * NUM_HEADS + h) * S_LEN + s) * HEAD_DIM + d;
                    float sc = (kind == 0) ? SCEXP : 1.0f;   // fold softmax scale into q
                    #pragma unroll
                    for (int r = 0; r < 4; r++)
                        dst[(size_t)r * HEAD_DIM] = f2bf((acc[mt][nt][r] + bb) * sc);
                } else {
                    unsigned int lo = pkrtz(acc[mt][nt][0] + bb, acc[mt][nt][1] + bb);
                    unsigned int hi = pkrtz(acc[mt][nt][2] + bb, acc[mt][nt][3] + bb);
                    *(uint2*)(out2 + ((size_t)(b * NUM_HEADS + h) * HEAD_DIM + d) * S_LEN + s) =
                        make_uint2(lo, hi);
                }
            }
        }
    }
}

// ---------------- MFMA flash attention, split-K(4), 24KB LDS ----------------
// Grid (NPH, SPLITK). Single-buffered K/V in LDS; next chunk prefetched into REGISTERS.
// launch_bounds(256,4): VGPR cap 128 -> no spill (r7's (256,6) spilled). Residency is
// LDS-limited at 24KB -> 6 blocks/CU; split-K(4) supplies 7.5 working blocks/CU to fill it.
__global__ __launch_bounds__(256, 4) void attn_kernel(
    const unsigned short* __restrict__ Q, const unsigned short* __restrict__ K,
    const unsigned short* __restrict__ Vtg, const int* __restrict__ work,
    unsigned short* __restrict__ opart, float* __restrict__ lpart)
{
    const int bx = blockIdx.x, half = blockIdx.y;
    const int pair = bx >> 4, h = bx & 15;
    const int tid  = threadIdx.x;
    const int w    = tid >> 6, lane = tid & 63;
    const int quad = lane >> 4, l16 = lane & 15;

    if (pair >= work[0]) return;                 // dropped: combine zero-fills
    const int e = work[1 + pair];
    const int b = e >> 5, qblk = e & 31;

    __shared__ unsigned short Kbuf[BS * HEAD_DIM];   // bf16, swizzled 16B chunks, 8KB
    __shared__ unsigned short Vbuf[HEAD_DIM * BS];   // fp16, swizzled 16B chunks, 8KB
    __shared__ unsigned short Pt[4][16 * 64];        // fp16 per-wave, 8KB

    const int KEYS = S_LEN / SPLITK;                 // 512 keys per block
    const int NCH  = KEYS / BS;                      // 8 chunks
    const size_t bh = (size_t)(b * NUM_HEADS + h);
    const unsigned short* Kb = K + bh * S_LEN * HEAD_DIM + (size_t)half * KEYS * HEAD_DIM;
    const unsigned short* Vb = Vtg + bh * HEAD_DIM * S_LEN + (size_t)half * KEYS;  // [dim][S]
    const unsigned short* Qb = Q + bh * S_LEN * HEAD_DIM;

    const int qrow = qblk * BS + w * 16 + l16;
    bf16x8 qf[2];
    #pragma unroll
    for (int ks = 0; ks < 2; ks++)
        qf[ks] = *(const bf16x8*)(Qb + (size_t)qrow * HEAD_DIM + ks * 32 + quad * 8);

    f32x4 o[4];
    #pragma unroll
    for (int mt = 0; mt < 4; mt++) o[mt] = (f32x4){0.f, 0.f, 0.f, 0.f};
    float l = 0.f;

    // staging slots: s = w*128 + {0,64} + lane; row = s>>3, swz chunk (s&7)^(row&7)
    const int sA = w * 128 + lane, sB = sA + 64;
    const int rA = sA >> 3, cA = (sA & 7) ^ (rA & 7);
    const int rB = sB >> 3, cB = (sB & 7) ^ (rB & 7);
    const size_t koA = (size_t)rA * HEAD_DIM + cA * 8, koB = (size_t)rB * HEAD_DIM + cB * 8;
    const size_t voA = (size_t)rA * S_LEN + cA * 8,    voB = (size_t)rB * S_LEN + cB * 8;

    uint4 kr0, kr1, vr0, vr1;
    #define LOADREGS(kc_)                                                       \
        {                                                                       \
            const unsigned short* kg_ = Kb + (size_t)(kc_) * BS * HEAD_DIM;     \
            const unsigned short* vg_ = Vb + (size_t)(kc_) * BS;                \
            kr0 = *(const uint4*)(kg_ + koA); kr1 = *(const uint4*)(kg_ + koB); \
            vr0 = *(const uint4*)(vg_ + voA); vr1 = *(const uint4*)(vg_ + voB); \
        }
    #define WRITELDS()                                                          \
        {                                                                       \
            *(uint4*)&Kbuf[(size_t)sA * 8] = kr0;                               \
            *(uint4*)&Kbuf[(size_t)sB * 8] = kr1;                               \
            *(uint4*)&Vbuf[(size_t)sA * 8] = vr0;                               \
            *(uint4*)&Vbuf[(size_t)sB * 8] = vr1;                               \
        }

    LOADREGS(0)
    WRITELDS()
    __syncthreads();

    for (int kc = 0; kc < NCH; kc++) {
        if (kc + 1 < NCH) LOADREGS(kc + 1)       // global latency hides under compute

        // S^T[key][qrow] = K · Q^T (bf16; q pre-scaled by SCEXP)
        f32x4 st[4];
        #pragma unroll
        for (int mt = 0; mt < 4; mt++) {
            f32x4 acc = {0.f, 0.f, 0.f, 0.f};
            #pragma unroll
            for (int ks = 0; ks < 2; ks++) {
                int kk = mt * 16 + l16;
                bf16x8 kf = *(const bf16x8*)&Kbuf[(size_t)(kk * 8 + ((ks * 4 + quad) ^ (kk & 7))) * 8];
                acc = __builtin_amdgcn_mfma_f32_16x16x32_bf16(kf, qf[ks], acc, 0, 0, 0);
            }
            st[mt] = acc;
        }

        // no-max softmax: p = exp2(st) (scale already folded into q)
        float pv[16], sum = 0.f;
        #pragma unroll
        for (int mt = 0; mt < 4; mt++)
            #pragma unroll
            for (int r = 0; r < 4; r++) {
                float ex = exp2f(st[mt][r]);
                pv[mt * 4 + r] = ex; sum += ex;
            }
        sum += __shfl_xor(sum, 16, 64);
        sum += __shfl_xor(sum, 32, 64);
        l += sum;

        // P^T -> Pt[w] fp16: row l16, 16B chunk index swizzled by ^(l16&7)
        #pragma unroll
        for (int mt = 0; mt < 4; mt++) {
            unsigned int lo = pkrtz(pv[mt * 4 + 0], pv[mt * 4 + 1]);
            unsigned int hi = pkrtz(pv[mt * 4 + 2], pv[mt * 4 + 3]);
            int c16 = 2 * mt + (quad >> 1);
            *(uint2*)&Pt[w][l16 * 64 + ((c16 ^ (l16 & 7)) * 8 + (quad & 1) * 4)] = make_uint2(lo, hi);
        }

        // O^T += V^T · P^T (fp16 MFMA)
        #pragma unroll
        for (int ks = 0; ks < 2; ks++) {
            f16x8 pf = *(const f16x8*)&Pt[w][l16 * 64 + (((4 * ks + quad) ^ (l16 & 7)) * 8)];
            #pragma unroll
            for (int mt = 0; mt < 4; mt++) {
                int d = mt * 16 + l16;
                f16x8 vf = *(const f16x8*)&Vbuf[(size_t)(d * 8 + ((ks * 4 + quad) ^ (d & 7))) * 8];
                o[mt] = __builtin_amdgcn_mfma_f32_16x16x32_f16(vf, pf, o[mt], 0, 0, 0);
            }
        }

        __syncthreads();                          // all waves done reading Kbuf/Vbuf
        if (kc + 1 < NCH) {
            WRITELDS()                            // stage next chunk from registers
            __syncthreads();
        }
    }

    // partial epilogue: fp16 O^T dump (coalesced) + l
    unsigned short* ob = opart + ((size_t)(half * NPH + bx)) * 4096 + tid * 16;
    uint4 w0, w1;
    w0.x = pkrtz(o[0][0], o[0][1]); w0.y = pkrtz(o[0][2], o[0][3]);
    w0.z = pkrtz(o[1][0], o[1][1]); w0.w = pkrtz(o[1][2], o[1][3]);
    w1.x = pkrtz(o[2][0], o[2][1]); w1.y = pkrtz(o[2][2], o[2][3]);
    w1.z = pkrtz(o[3][0], o[3][1]); w1.w = pkrtz(o[3][2], o[3][3]);
    *(uint4*)ob = w0;
    *(uint4*)(ob + 8) = w1;
    if (quad == 0) lpart[(size_t)(half * NPH + bx) * 64 + w * 16 + l16] = l;
}

// ---------------- combine: sum SPLITK partials, normalize, transpose, store bf16 ----------------
__global__ __launch_bounds__(256) void attn_combine(
    const unsigned short* __restrict__ opart, const float* __restrict__ lpart,
    const int* __restrict__ work, unsigned short* __restrict__ attn_out)
{
    const int bx = blockIdx.x;
    const int pair = bx >> 4, h = bx & 15;
    const int tid  = threadIdx.x;
    const int w    = tid >> 6, lane = tid & 63;
    const int quad = lane >> 4, l16 = lane & 15;

    const int e = work[1 + pair];
    const int b = e >> 5, qblk = e & 31;
    unsigned short* ablk = attn_out + ((size_t)(b * S_LEN + qblk * BS)) * D_MODEL + h * HEAD_DIM;

    if (pair >= work[0]) {                       // dropped: zero-fill
        uint4 z = make_uint4(0, 0, 0, 0);
        #pragma unroll
        for (int i = 0; i < 2; i++) {
            int u = tid + i * 256;
            int row = u >> 3, c8 = (u & 7) * 8;
            *(uint4*)(ablk + (size_t)row * D_MODEL + c8) = z;
        }
        return;
    }

    __shared__ float Obuf[4][HEAD_DIM * 17];

    float osum[16];
    #pragma unroll
    for (int j = 0; j < 16; j++) osum[j] = 0.f;
    float lsum = 0.f;
    #pragma unroll
    for (int hf = 0; hf < SPLITK; hf++) {
        const f16x8* pp = (const f16x8*)(opart + ((size_t)hf * NPH + bx) * 4096 + tid * 16);
        f16x8 a0 = pp[0], a1 = pp[1];
        #pragma unroll
        for (int j = 0; j < 8; j++) {
            osum[j]     += (float)a0[j];
            osum[8 + j] += (float)a1[j];
        }
        lsum += lpart[((size_t)hf * NPH + bx) * 64 + w * 16 + l16];
    }
    float inv = 1.0f / lsum;

    #pragma unroll
    for (int mt = 0; mt < 4; mt++)
        #pragma unroll
        for (int r = 0; r < 4; r++)
            Obuf[w][(mt * 16 + quad * 4 + r) * 17 + l16] = osum[mt * 4 + r] * inv;
    // wave-private buffer: in-wave ordering via compiler waitcnts
    #pragma unroll
    for (int i = 0; i < 4; i++) {
        int uu = lane + 64 * i;
        int row = uu >> 4, d4 = (uu & 15) * 4;
        float x0 = Obuf[w][(d4 + 0) * 17 + row];
        float x1 = Obuf[w][(d4 + 1) * 17 + row];
        float x2 = Obuf[w][(d4 + 2) * 17 + row];
        float x3 = Obuf[w][(d4 + 3) * 17 + row];
        unsigned int lo = (unsigned int)f2bf(x0) | ((unsigned int)f2bf(x1) << 16);
        unsigned int hi = (unsigned int)f2bf(x2) | ((unsigned int)f2bf(x3) << 16);
        *(uint2*)(ablk + (size_t)(w * 16 + row) * D_MODEL + d4) = make_uint2(lo, hi);
    }
}

extern "C" void kernel_launch(void* const* d_in, const int* in_sizes, int n_in,
                              void* d_out, int out_size, void* d_ws, size_t ws_size,
                              hipStream_t stream) {
    const float* x  = (const float*)d_in[0];
    const float* G  = (const float*)d_in[1];
    const float* Wq = (const float*)d_in[2];
    const float* bq = (const float*)d_in[3];
    const float* Wk = (const float*)d_in[4];
    const float* bk = (const float*)d_in[5];
    const float* Wv = (const float*)d_in[6];
    const float* bv = (const float*)d_in[7];
    const float* Wo = (const float*)d_in[8];
    const float* bo = (const float*)d_in[9];
    float* out = (float*)d_out;

    char* wsp = (char*)d_ws;
    int* keep = (int*)wsp;                                           // 64 ints
    int* work = keep + 64;                                           // 65 ints
    unsigned short* xb    = (unsigned short*)(wsp + 1024);           // 4M elems bf16
    unsigned short* wcat  = xb + (size_t)M_ROWS * D_MODEL;           // 3M elems bf16
    unsigned short* wot   = wcat + (size_t)3 * 1024 * 1024;          // 1M elems bf16
    unsigned short* q     = wot + (size_t)1024 * 1024;               // bf16 (pre-scaled)
    unsigned short* k     = q + QKV_ELEMS;                           // bf16
    unsigned short* vt    = k + QKV_ELEMS;                           // fp16 (transposed)
    unsigned short* attnb = vt + QKV_ELEMS;                          // bf16
    unsigned short* opart = attnb + (size_t)M_ROWS * D_MODEL;        // SPLITK*NPH*4096 fp16
    float* lpart = (float*)(opart + (size_t)SPLITK * NPH * 4096);    // SPLITK*NPH*64 fp32

    prep_kernel<<<3073, 256, 0, stream>>>(x, G, Wq, Wk, Wv, Wo, xb, wcat, wot, keep, work);

    // fused QKV: [4096 x 3072]
    mfma_gemm<<<dim3(3072 / 128, M_ROWS / 128), 256, 0, stream>>>(
        xb, wcat, bq, bk, bv, keep, (void*)q, k, vt, 1);

    attn_kernel<<<dim3(NPH, SPLITK), 256, 0, stream>>>(q, k, vt, work, opart, lpart);
    attn_combine<<<NPH, 256, 0, stream>>>(opart, lpart, work, attnb);

    // output projection: [4096 x 1024]
    mfma_gemm<<<dim3(1024 / 128, M_ROWS / 128), 256, 0, stream>>>(
        attnb, wot, bo, nullptr, nullptr, keep, (void*)out, nullptr, nullptr, 0);
}

// Round 10
// 191.846 us; speedup vs baseline: 1.1833x; 1.0296x over previous
//
#include <hip/hip_runtime.h>
#include <math.h>

#define D_MODEL   1024
#define NUM_HEADS 16
#define HEAD_DIM  64
#define BS        64
#define NB        32
#define S_LEN     2048
#define BATCH     2
#define M_ROWS    (BATCH * S_LEN)  // 4096
#define THRESH    0.99f
#define SCEXP     0.18033688f      // 0.125 * log2(e); folded into q at QKV epilogue
#define NPH       (BATCH * NB * NUM_HEADS)   // 1024 (pair,head) work items
#define SPLITK    4                          // key-range split for attention

typedef __attribute__((ext_vector_type(8))) short bf16x8;
typedef __attribute__((ext_vector_type(8))) _Float16 f16x8;
typedef __attribute__((ext_vector_type(2))) __fp16 fp16v2;   // native return type of cvt_pkrtz
typedef __attribute__((ext_vector_type(4))) float f32x4;

__device__ __forceinline__ unsigned short f2bf(float f) {
    unsigned int u = __float_as_uint(f);
    u += 0x7fff + ((u >> 16) & 1);   // RNE
    return (unsigned short)(u >> 16);
}

__device__ __forceinline__ unsigned int pkrtz(float a, float b) {
    fp16v2 r = __builtin_amdgcn_cvt_pkrtz(a, b);   // v_cvt_pkrtz_f16_f32, 1 instr
    return __builtin_bit_cast(unsigned int, r);
}

// async global->LDS, 16B per lane; lds dest = wave-uniform base + lane*16
__device__ __forceinline__ void gload16(const void* gptr, void* lptr) {
    __builtin_amdgcn_global_load_lds(
        (const __attribute__((address_space(1))) void*)gptr,
        (__attribute__((address_space(3))) void*)lptr, 16, 0, 0);
}

// ---------------- fused prep: convert_x | transpose_w | compact ----------------
__global__ __launch_bounds__(256) void prep_kernel(
    const float* __restrict__ x, const float* __restrict__ G,
    const float* __restrict__ Wq, const float* __restrict__ Wk,
    const float* __restrict__ Wv, const float* __restrict__ Wo,
    unsigned short* __restrict__ xb, unsigned short* __restrict__ wcat,
    unsigned short* __restrict__ wot, int* __restrict__ keep, int* __restrict__ work)
{
    const int bid = blockIdx.x, tid = threadIdx.x;
    __shared__ float T[64][65];

    if (bid < 2048) {                       // ---- convert x ----
        size_t i = ((size_t)bid * 256 + tid) * 8;
        float4 a = *(const float4*)(x + i);
        float4 b = *(const float4*)(x + i + 4);
        uint4 o;
        o.x = (unsigned int)f2bf(a.x) | ((unsigned int)f2bf(a.y) << 16);
        o.y = (unsigned int)f2bf(a.z) | ((unsigned int)f2bf(a.w) << 16);
        o.z = (unsigned int)f2bf(b.x) | ((unsigned int)f2bf(b.y) << 16);
        o.w = (unsigned int)f2bf(b.z) | ((unsigned int)f2bf(b.w) << 16);
        *(uint4*)(xb + i) = o;
    } else if (bid < 3072) {                // ---- transpose W ----
        int i = bid - 2048;
        int mat = i >> 8, rem = i & 255;
        int k0 = (rem & 15) * 64, n0 = (rem >> 4) * 64;
        const float* W = (mat == 0) ? Wq : (mat == 1) ? Wk : (mat == 2) ? Wv : Wo;
        int rr = tid >> 4, c4 = (tid & 15) * 4;
        #pragma unroll
        for (int j = 0; j < 4; j++) {
            int row = rr + j * 16;
            float4 v = *(const float4*)(W + (size_t)(k0 + row) * 1024 + n0 + c4);
            T[row][c4 + 0] = v.x; T[row][c4 + 1] = v.y;
            T[row][c4 + 2] = v.z; T[row][c4 + 3] = v.w;
        }
        __syncthreads();
        unsigned short* dst = (mat < 3) ? (wcat + (size_t)mat * 1024 * 1024) : wot;
        #pragma unroll
        for (int j = 0; j < 4; j++) {
            int n = rr + j * 16;
            unsigned int lo = (unsigned int)f2bf(T[c4 + 0][n]) | ((unsigned int)f2bf(T[c4 + 1][n]) << 16);
            unsigned int hi = (unsigned int)f2bf(T[c4 + 2][n]) | ((unsigned int)f2bf(T[c4 + 3][n]) << 16);
            *(uint2*)(dst + (size_t)(n0 + n) * 1024 + k0 + c4) = make_uint2(lo, hi);
        }
    } else {                                // ---- compact (wave 0 only) ----
        if (tid < 64) {
            int t = tid;
            const float4* g = (const float4*)(G + (size_t)t * 64);
            float mx = 0.f;
            #pragma unroll
            for (int j = 0; j < 16; j++) {
                float4 v = g[j];
                mx = fmaxf(mx, fmaxf(fmaxf(fabsf(v.x), fabsf(v.y)), fmaxf(fabsf(v.z), fabsf(v.w))));
            }
            bool k = (mx >= THRESH);
            unsigned long long bal = __ballot(k);
            int nk = __popcll(bal);
            unsigned long long below = bal & ((1ull << t) - 1ull);
            int nbelow = (int)__popcll(below);
            keep[t] = k ? 1 : 0;
            if (t == 0) work[0] = nk;
            int pos = k ? nbelow : (nk + t - nbelow);
            work[1 + pos] = t;
        }
    }
}

// ---------------- QKV GEMM: 64x128 tiles, LDS-repacked coalesced epilogue ----------------
// A = xb [4096][1024] bf16, Bt = wcat [3072][1024] bf16.
// n0<1024 -> q (bias bq, *SCEXP) into qk cols [0,1024); n0 in [1024,2048) -> k into qk cols
// [1024,2048); n0>=2048 -> V^T fp16 into vt[(b*16+h)*64+d][2048].
__global__ __launch_bounds__(256, 4) void gemm_qkv(
    const unsigned short* __restrict__ A, const unsigned short* __restrict__ Bt,
    const float* __restrict__ bq, const float* __restrict__ bk, const float* __restrict__ bv,
    const int* __restrict__ keep, unsigned short* __restrict__ qk, unsigned short* __restrict__ vt)
{
    const int n0 = blockIdx.x * 128, m0 = blockIdx.y * 64;
    const int tid = threadIdx.x, w = tid >> 6, lane = tid & 63;
    const int quad = lane >> 4, l16 = lane & 15;
    const int kindb = n0 >> 10;          // 0=q, 1=k, 2=v (blocks are kind-homogeneous)
    if (kindb == 0 && !keep[blockIdx.y]) return;

    __shared__ union {
        struct { unsigned short As[2][64 * 32]; unsigned short Bs[2][128 * 32]; } s;  // 24 KB
        unsigned short qkr[64 * 136];    // q/k repack [row][col], stride 136 (16B-aligned rows)
        unsigned short vr[128 * 72];     // V repack [col][s], stride 72
    } u;

    f32x4 acc[4][2];
    #pragma unroll
    for (int mt = 0; mt < 4; mt++)
        #pragma unroll
        for (int nt = 0; nt < 2; nt++) acc[mt][nt] = (f32x4){0.f, 0.f, 0.f, 0.f};

    #define QSTAGE(it_, p_)                                                             \
        {                                                                               \
            int k0_ = (it_) * 32;                                                       \
            { int s_ = w * 64 + lane; int row = s_ >> 2, cl = s_ & 3;                   \
              int c = cl ^ ((row >> 1) & 3);                                            \
              gload16(A + (size_t)(m0 + row) * 1024 + k0_ + c * 8,                      \
                      &u.s.As[p_][(w * 64) * 8]); }                                     \
            _Pragma("unroll")                                                           \
            for (int j = 0; j < 2; j++) {                                               \
                int s_ = w * 128 + j * 64 + lane; int row = s_ >> 2, cl = s_ & 3;       \
                int c = cl ^ ((row >> 1) & 3);                                          \
                gload16(Bt + (size_t)(n0 + row) * 1024 + k0_ + c * 8,                   \
                        &u.s.Bs[p_][(w * 128 + j * 64) * 8]);                           \
            }                                                                           \
        }

    QSTAGE(0, 0)

    for (int it = 0; it < 32; it++) {
        const int p = it & 1;
        __syncthreads();
        if (it + 1 < 32) QSTAGE(it + 1, (it + 1) & 1)

        bf16x8 af[4], bfr[2];
        #pragma unroll
        for (int mt = 0; mt < 4; mt++) {
            int row = mt * 16 + l16;
            int cl = quad ^ ((row >> 1) & 3);
            af[mt] = *(const bf16x8*)&u.s.As[p][(row * 4 + cl) * 8];
        }
        #pragma unroll
        for (int nt = 0; nt < 2; nt++) {
            int row = w * 32 + nt * 16 + l16;
            int cl = quad ^ ((row >> 1) & 3);
            bfr[nt] = *(const bf16x8*)&u.s.Bs[p][(row * 4 + cl) * 8];
        }
        #pragma unroll
        for (int mt = 0; mt < 4; mt++)
            #pragma unroll
            for (int nt = 0; nt < 2; nt++)
                acc[mt][nt] = __builtin_amdgcn_mfma_f32_16x16x32_bf16(af[mt], bfr[nt], acc[mt][nt], 0, 0, 0);
    }
    __syncthreads();   // staging done everywhere before repack overlay

    if (kindb < 2) {
        const float* bp = (kindb == 0) ? bq : bk;
        const float sc = (kindb == 0) ? SCEXP : 1.0f;
        #pragma unroll
        for (int nt = 0; nt < 2; nt++) {
            int coll = w * 32 + nt * 16 + l16;
            float bb = bp[(n0 & 1023) + coll];
            #pragma unroll
            for (int mt = 0; mt < 4; mt++)
                #pragma unroll
                for (int r = 0; r < 4; r++) {
                    int row = mt * 16 + quad * 4 + r;
                    u.qkr[row * 136 + coll] = f2bf((acc[mt][nt][r] + bb) * sc);
                }
        }
        __syncthreads();
        #pragma unroll
        for (int i = 0; i < 4; i++) {
            int s_ = tid + i * 256;              // 1024 slots: 64 rows x 16 chunks
            int row = s_ >> 4, c16 = s_ & 15;
            uint4 v = *(const uint4*)&u.qkr[row * 136 + c16 * 8];
            *(uint4*)(qk + (size_t)(m0 + row) * 2048 + n0 + c16 * 8) = v;
        }
    } else {
        #pragma unroll
        for (int nt = 0; nt < 2; nt++) {
            int coll = w * 32 + nt * 16 + l16;
            float bb = bv[(n0 - 2048) + coll];
            #pragma unroll
            for (int mt = 0; mt < 4; mt++) {
                int s0 = mt * 16 + quad * 4;
                uint2 pv;
                pv.x = pkrtz(acc[mt][nt][0] + bb, acc[mt][nt][1] + bb);
                pv.y = pkrtz(acc[mt][nt][2] + bb, acc[mt][nt][3] + bb);
                *(uint2*)&u.vr[coll * 72 + s0] = pv;
            }
        }
        __syncthreads();
        const int b_ = m0 >> 11, sbase = m0 & 2047;
        #pragma unroll
        for (int i = 0; i < 4; i++) {
            int s_ = tid + i * 256;              // 1024 slots: 128 cols x 8 s-chunks
            int coll = s_ >> 3, ch = s_ & 7;
            uint4 v = *(const uint4*)&u.vr[coll * 72 + ch * 8];
            int colg = n0 - 2048 + coll;
            int h_ = colg >> 6, d = colg & 63;
            *(uint4*)(vt + ((size_t)(b_ * NUM_HEADS + h_) * HEAD_DIM + d) * 2048 + sbase + ch * 8) = v;
        }
    }
}

// ---------------- output GEMM: 64x64 tiles (grid-starvation fix: 1024 blocks) ----------------
__global__ __launch_bounds__(256, 4) void gemm_out(
    const unsigned short* __restrict__ A, const unsigned short* __restrict__ Bt,
    const float* __restrict__ bo, const int* __restrict__ keep, float* __restrict__ out)
{
    const int n0 = blockIdx.x * 64, m0 = blockIdx.y * 64;
    const int tid = threadIdx.x, w = tid >> 6, lane = tid & 63;
    const int quad = lane >> 4, l16 = lane & 15;
    const int wm = w >> 1, wn = w & 1;

    if (!keep[blockIdx.y]) {                 // dropped: bias rows
        #pragma unroll
        for (int i = 0; i < 4; i++) {
            int s_ = tid + i * 256;          // 1024 float4 slots: 64 rows x 16
            int row = s_ >> 4, c = (s_ & 15) * 4;
            *(float4*)(out + (size_t)(m0 + row) * 1024 + n0 + c) = *(const float4*)(bo + n0 + c);
        }
        return;
    }

    __shared__ unsigned short Asl[2][64 * 32];
    __shared__ unsigned short Bsl[2][64 * 32];

    f32x4 acc[2][2];
    #pragma unroll
    for (int mt = 0; mt < 2; mt++)
        #pragma unroll
        for (int nt = 0; nt < 2; nt++) acc[mt][nt] = (f32x4){0.f, 0.f, 0.f, 0.f};

    #define OSTAGE(it_, p_)                                                             \
        {                                                                               \
            int k0_ = (it_) * 32;                                                       \
            int s_ = w * 64 + lane; int row = s_ >> 2, cl = s_ & 3;                     \
            int c = cl ^ ((row >> 1) & 3);                                              \
            gload16(A  + (size_t)(m0 + row) * 1024 + k0_ + c * 8, &Asl[p_][(w * 64) * 8]); \
            gload16(Bt + (size_t)(n0 + row) * 1024 + k0_ + c * 8, &Bsl[p_][(w * 64) * 8]); \
        }

    OSTAGE(0, 0)

    for (int it = 0; it < 32; it++) {
        const int p = it & 1;
        __syncthreads();
        if (it + 1 < 32) OSTAGE(it + 1, (it + 1) & 1)

        bf16x8 af[2], bfr[2];
        #pragma unroll
        for (int mt = 0; mt < 2; mt++) {
            int row = wm * 32 + mt * 16 + l16;
            int cl = quad ^ ((row >> 1) & 3);
            af[mt] = *(const bf16x8*)&Asl[p][(row * 4 + cl) * 8];
        }
        #pragma unroll
        for (int nt = 0; nt < 2; nt++) {
            int row = wn * 32 + nt * 16 + l16;
            int cl = quad ^ ((row >> 1) & 3);
            bfr[nt] = *(const bf16x8*)&Bsl[p][(row * 4 + cl) * 8];
        }
        #pragma unroll
        for (int mt = 0; mt < 2; mt++)
            #pragma unroll
            for (int nt = 0; nt < 2; nt++)
                acc[mt][nt] = __builtin_amdgcn_mfma_f32_16x16x32_bf16(af[mt], bfr[nt], acc[mt][nt], 0, 0, 0);
    }

    #pragma unroll
    for (int nt = 0; nt < 2; nt++) {
        int col = n0 + wn * 32 + nt * 16 + l16;
        float bb = bo[col];
        #pragma unroll
        for (int mt = 0; mt < 2; mt++) {
            int mb = m0 + wm * 32 + mt * 16 + quad * 4;
            #pragma unroll
            for (int r = 0; r < 4; r++)
                out[(size_t)(mb + r) * 1024 + col] = acc[mt][nt][r] + bb;
        }
    }
}

// ---------------- MFMA flash attention, split-K(4), 24KB LDS, flat q/k ----------------
__global__ __launch_bounds__(256, 4) void attn_kernel(
    const unsigned short* __restrict__ qk, const unsigned short* __restrict__ Vtg,
    const int* __restrict__ work,
    unsigned short* __restrict__ opart, float* __restrict__ lpart)
{
    const int bx = blockIdx.x, half = blockIdx.y;
    const int pair = bx >> 4, h = bx & 15;
    const int tid  = threadIdx.x;
    const int w    = tid >> 6, lane = tid & 63;
    const int quad = lane >> 4, l16 = lane & 15;

    if (pair >= work[0]) return;                 // dropped: combine zero-fills
    const int e = work[1 + pair];
    const int b = e >> 5, qblk = e & 31;

    __shared__ unsigned short Kbuf[BS * HEAD_DIM];   // bf16, swizzled 16B chunks, 8KB
    __shared__ unsigned short Vbuf[HEAD_DIM * BS];   // fp16, swizzled 16B chunks, 8KB
    __shared__ unsigned short Pt[4][16 * 64];        // fp16 per-wave, 8KB

    const int KEYS = S_LEN / SPLITK;                 // 512 keys per block
    const int NCH  = KEYS / BS;                      // 8 chunks
    const unsigned short* Qb = qk + (size_t)(b * S_LEN) * 2048 + h * 64;
    const unsigned short* Kb = qk + (size_t)(b * S_LEN + half * KEYS) * 2048 + 1024 + h * 64;
    const unsigned short* Vb = Vtg + (size_t)(b * NUM_HEADS + h) * HEAD_DIM * 2048 + half * KEYS;

    const int qrow = qblk * BS + w * 16 + l16;
    bf16x8 qf[2];
    #pragma unroll
    for (int ks = 0; ks < 2; ks++)
        qf[ks] = *(const bf16x8*)(Qb + (size_t)qrow * 2048 + ks * 32 + quad * 8);

    f32x4 o[4];
    #pragma unroll
    for (int mt = 0; mt < 4; mt++) o[mt] = (f32x4){0.f, 0.f, 0.f, 0.f};
    float l = 0.f;

    // staging slots: s = w*128 + {0,64} + lane; row = s>>3, swz chunk (s&7)^(row&7)
    const int sA = w * 128 + lane, sB = sA + 64;
    const int rA = sA >> 3, cA = (sA & 7) ^ (rA & 7);
    const int rB = sB >> 3, cB = (sB & 7) ^ (rB & 7);
    const size_t koA = (size_t)rA * 2048 + cA * 8, koB = (size_t)rB * 2048 + cB * 8;

    uint4 kr0, kr1, vr0, vr1;
    #define LOADREGS(kc_)                                                       \
        {                                                                       \
            const unsigned short* kg_ = Kb + (size_t)(kc_) * BS * 2048;         \
            const unsigned short* vg_ = Vb + (size_t)(kc_) * BS;                \
            kr0 = *(const uint4*)(kg_ + koA); kr1 = *(const uint4*)(kg_ + koB); \
            vr0 = *(const uint4*)(vg_ + koA); vr1 = *(const uint4*)(vg_ + koB); \
        }
    #define WRITELDS()                                                          \
        {                                                                       \
            *(uint4*)&Kbuf[(size_t)sA * 8] = kr0;                               \
            *(uint4*)&Kbuf[(size_t)sB * 8] = kr1;                               \
            *(uint4*)&Vbuf[(size_t)sA * 8] = vr0;                               \
            *(uint4*)&Vbuf[(size_t)sB * 8] = vr1;                               \
        }

    LOADREGS(0)
    WRITELDS()
    __syncthreads();

    for (int kc = 0; kc < NCH; kc++) {
        if (kc + 1 < NCH) LOADREGS(kc + 1)       // global latency hides under compute

        // S^T[key][qrow] = K · Q^T (bf16; q pre-scaled by SCEXP)
        f32x4 st[4];
        #pragma unroll
        for (int mt = 0; mt < 4; mt++) {
            f32x4 acc = {0.f, 0.f, 0.f, 0.f};
            #pragma unroll
            for (int ks = 0; ks < 2; ks++) {
                int kk = mt * 16 + l16;
                bf16x8 kf = *(const bf16x8*)&Kbuf[(size_t)(kk * 8 + ((ks * 4 + quad) ^ (kk & 7))) * 8];
                acc = __builtin_amdgcn_mfma_f32_16x16x32_bf16(kf, qf[ks], acc, 0, 0, 0);
            }
            st[mt] = acc;
        }

        // no-max softmax: p = exp2(st)
        float pv[16], sum = 0.f;
        #pragma unroll
        for (int mt = 0; mt < 4; mt++)
            #pragma unroll
            for (int r = 0; r < 4; r++) {
                float ex = exp2f(st[mt][r]);
                pv[mt * 4 + r] = ex; sum += ex;
            }
        sum += __shfl_xor(sum, 16, 64);
        sum += __shfl_xor(sum, 32, 64);
        l += sum;

        // P^T -> Pt[w] fp16: row l16, 16B chunk index swizzled by ^(l16&7)
        #pragma unroll
        for (int mt = 0; mt < 4; mt++) {
            unsigned int lo = pkrtz(pv[mt * 4 + 0], pv[mt * 4 + 1]);
            unsigned int hi = pkrtz(pv[mt * 4 + 2], pv[mt * 4 + 3]);
            int c16 = 2 * mt + (quad >> 1);
            *(uint2*)&Pt[w][l16 * 64 + ((c16 ^ (l16 & 7)) * 8 + (quad & 1) * 4)] = make_uint2(lo, hi);
        }

        // O^T += V^T · P^T (fp16 MFMA)
        #pragma unroll
        for (int ks = 0; ks < 2; ks++) {
            f16x8 pf = *(const f16x8*)&Pt[w][l16 * 64 + (((4 * ks + quad) ^ (l16 & 7)) * 8)];
            #pragma unroll
            for (int mt = 0; mt < 4; mt++) {
                int d = mt * 16 + l16;
                f16x8 vf = *(const f16x8*)&Vbuf[(size_t)(d * 8 + ((ks * 4 + quad) ^ (d & 7))) * 8];
                o[mt] = __builtin_amdgcn_mfma_f32_16x16x32_f16(vf, pf, o[mt], 0, 0, 0);
            }
        }

        __syncthreads();                          // all waves done reading Kbuf/Vbuf
        if (kc + 1 < NCH) {
            WRITELDS()                            // stage next chunk from registers
            __syncthreads();
        }
    }

    // partial epilogue: fp16 O^T dump (coalesced) + l
    unsigned short* ob = opart + ((size_t)(half * NPH + bx)) * 4096 + tid * 16;
    uint4 w0, w1;
    w0.x = pkrtz(o[0][0], o[0][1]); w0.y = pkrtz(o[0][2], o[0][3]);
    w0.z = pkrtz(o[1][0], o[1][1]); w0.w = pkrtz(o[1][2], o[1][3]);
    w1.x = pkrtz(o[2][0], o[2][1]); w1.y = pkrtz(o[2][2], o[2][3]);
    w1.z = pkrtz(o[3][0], o[3][1]); w1.w = pkrtz(o[3][2], o[3][3]);
    *(uint4*)ob = w0;
    *(uint4*)(ob + 8) = w1;
    if (quad == 0) lpart[(size_t)(half * NPH + bx) * 64 + w * 16 + l16] = l;
}

// ---------------- combine: sum SPLITK partials, normalize, transpose, store bf16 ----------------
__global__ __launch_bounds__(256) void attn_combine(
    const unsigned short* __restrict__ opart, const float* __restrict__ lpart,
    const int* __restrict__ work, unsigned short* __restrict__ attn_out)
{
    const int bx = blockIdx.x;
    const int pair = bx >> 4, h = bx & 15;
    const int tid  = threadIdx.x;
    const int w    = tid >> 6, lane = tid & 63;
    const int quad = lane >> 4, l16 = lane & 15;

    const int e = work[1 + pair];
    const int b = e >> 5, qblk = e & 31;
    unsigned short* ablk = attn_out + ((size_t)(b * S_LEN + qblk * BS)) * D_MODEL + h * HEAD_DIM;

    if (pair >= work[0]) {                       // dropped: zero-fill
        uint4 z = make_uint4(0, 0, 0, 0);
        #pragma unroll
        for (int i = 0; i < 2; i++) {
            int u = tid + i * 256;
            int row = u >> 3, c8 = (u & 7) * 8;
            *(uint4*)(ablk + (size_t)row * D_MODEL + c8) = z;
        }
        return;
    }

    __shared__ float Obuf[4][HEAD_DIM * 17];

    float osum[16];
    #pragma unroll
    for (int j = 0; j < 16; j++) osum[j] = 0.f;
    float lsum = 0.f;
    #pragma unroll
    for (int hf = 0; hf < SPLITK; hf++) {
        const f16x8* pp = (const f16x8*)(opart + ((size_t)hf * NPH + bx) * 4096 + tid * 16);
        f16x8 a0 = pp[0], a1 = pp[1];
        #pragma unroll
        for (int j = 0; j < 8; j++) {
            osum[j]     += (float)a0[j];
            osum[8 + j] += (float)a1[j];
        }
        lsum += lpart[((size_t)hf * NPH + bx) * 64 + w * 16 + l16];
    }
    float inv = 1.0f / lsum;

    #pragma unroll
    for (int mt = 0; mt < 4; mt++)
        #pragma unroll
        for (int r = 0; r < 4; r++)
            Obuf[w][(mt * 16 + quad * 4 + r) * 17 + l16] = osum[mt * 4 + r] * inv;
    #pragma unroll
    for (int i = 0; i < 4; i++) {
        int uu = lane + 64 * i;
        int row = uu >> 4, d4 = (uu & 15) * 4;
        float x0 = Obuf[w][(d4 + 0) * 17 + row];
        float x1 = Obuf[w][(d4 + 1) * 17 + row];
        float x2 = Obuf[w][(d4 + 2) * 17 + row];
        float x3 = Obuf[w][(d4 + 3) * 17 + row];
        unsigned int lo = (unsigned int)f2bf(x0) | ((unsigned int)f2bf(x1) << 16);
        unsigned int hi = (unsigned int)f2bf(x2) | ((unsigned int)f2bf(x3) << 16);
        *(uint2*)(ablk + (size_t)(w * 16 + row) * D_MODEL + d4) = make_uint2(lo, hi);
    }
}

extern "C" void kernel_launch(void* const* d_in, const int* in_sizes, int n_in,
                              void* d_out, int out_size, void* d_ws, size_t ws_size,
                              hipStream_t stream) {
    const float* x  = (const float*)d_in[0];
    const float* G  = (const float*)d_in[1];
    const float* Wq = (const float*)d_in[2];
    const float* bq = (const float*)d_in[3];
    const float* Wk = (const float*)d_in[4];
    const float* bk = (const float*)d_in[5];
    const float* Wv = (const float*)d_in[6];
    const float* bv = (const float*)d_in[7];
    const float* Wo = (const float*)d_in[8];
    const float* bo = (const float*)d_in[9];
    float* out = (float*)d_out;

    char* wsp = (char*)d_ws;
    int* keep = (int*)wsp;                                           // 64 ints
    int* work = keep + 64;                                           // 65 ints
    unsigned short* xb    = (unsigned short*)(wsp + 1024);           // 4M elems bf16
    unsigned short* wcat  = xb + (size_t)M_ROWS * D_MODEL;           // 3M elems bf16
    unsigned short* wot   = wcat + (size_t)3 * 1024 * 1024;          // 1M elems bf16
    unsigned short* qk    = wot + (size_t)1024 * 1024;               // [4096][2048] bf16
    unsigned short* vt    = qk + (size_t)M_ROWS * 2048;              // [B*H*64][2048] fp16
    unsigned short* attnb = vt + (size_t)BATCH * NUM_HEADS * HEAD_DIM * 2048;  // bf16
    unsigned short* opart = attnb + (size_t)M_ROWS * D_MODEL;        // SPLITK*NPH*4096 fp16
    float* lpart = (float*)(opart + (size_t)SPLITK * NPH * 4096);    // SPLITK*NPH*64 fp32

    prep_kernel<<<3073, 256, 0, stream>>>(x, G, Wq, Wk, Wv, Wo, xb, wcat, wot, keep, work);

    // fused QKV: [4096 x 3072], 64x128 tiles
    gemm_qkv<<<dim3(3072 / 128, M_ROWS / 64), 256, 0, stream>>>(
        xb, wcat, bq, bk, bv, keep, qk, vt);

    attn_kernel<<<dim3(NPH, SPLITK), 256, 0, stream>>>(qk, vt, work, opart, lpart);
    attn_combine<<<NPH, 256, 0, stream>>>(opart, lpart, work, attnb);

    // output projection: [4096 x 1024], 64x64 tiles
    gemm_out<<<dim3(1024 / 64, M_ROWS / 64), 256, 0, stream>>>(attnb, wot, bo, keep, out);
}